// Round 8
// baseline (2131.026 us; speedup 1.0000x reference)
//
#include <hip/hip_runtime.h>
#include <math.h>

#define BB 8
#define NN 512
#define DD 512
#define HH 8
#define DHH 64
#define FFF 2048
#define MEMM 4096
#define TOPKK 32
#define DEPTHH 6
#define NT (BB*NN)   /* 4096 tokens */
#define QKVS 1536    /* fused qkv row stride */

typedef __bf16 bf16x8 __attribute__((ext_vector_type(8)));
typedef __bf16 bf16x4 __attribute__((ext_vector_type(4)));
typedef float f32x4 __attribute__((ext_vector_type(4)));

// ---------------- LayerNorm (fp32 in, fp32 or bf16 out) ----------------
template <int OBF16>
__global__ __launch_bounds__(256) void ln_kernel(const float* __restrict__ xin,
                                                 const float* __restrict__ g,
                                                 const float* __restrict__ bt,
                                                 void* __restrict__ outv) {
  __shared__ float red[4];
  int tok = blockIdx.x;
  const float* xr = xin + (size_t)tok * DD;
  int t = threadIdx.x;
  float v0 = xr[t], v1 = xr[t + 256];
  float s = v0 + v1;
#pragma unroll
  for (int m = 32; m; m >>= 1) s += __shfl_xor(s, m, 64);
  if ((t & 63) == 0) red[t >> 6] = s;
  __syncthreads();
  float mean = (red[0] + red[1] + red[2] + red[3]) * (1.0f / 512.0f);
  float d0 = v0 - mean, d1 = v1 - mean;
  float vv = d0 * d0 + d1 * d1;
#pragma unroll
  for (int m = 32; m; m >>= 1) vv += __shfl_xor(vv, m, 64);
  __syncthreads();
  if ((t & 63) == 0) red[t >> 6] = vv;
  __syncthreads();
  float var = (red[0] + red[1] + red[2] + red[3]) * (1.0f / 512.0f);
  float inv = rsqrtf(var + 1e-5f);
  float o0 = d0 * inv * g[t] + bt[t];
  float o1 = d1 * inv * g[t + 256] + bt[t + 256];
  if (OBF16) {
    __bf16* out = (__bf16*)outv;
    out[(size_t)tok * DD + t] = (__bf16)o0;
    out[(size_t)tok * DD + t + 256] = (__bf16)o1;
  } else {
    float* out = (float*)outv;
    out[(size_t)tok * DD + t] = o0;
    out[(size_t)tok * DD + t + 256] = o1;
  }
}

__device__ inline float gelu_f(float x) {
  float x3 = x * x * x;
  return 0.5f * x * (1.0f + tanhf(0.7978845608028654f * (x + 0.044715f * x3)));
}

// --------- batched weight transpose+convert: all 6 weights, one launch ------
__global__ __launch_bounds__(256) void transpose_all_kernel(
    const float* __restrict__ Wq, const float* __restrict__ Wk,
    const float* __restrict__ Wv, const float* __restrict__ Wo,
    const float* __restrict__ W1, const float* __restrict__ W2,
    __bf16* __restrict__ wqT, __bf16* __restrict__ wkT,
    __bf16* __restrict__ wvT, __bf16* __restrict__ woT,
    __bf16* __restrict__ w1T, __bf16* __restrict__ w2T) {
  __shared__ float tile[32][33];
  int tid = blockIdx.x;
  const float* src; __bf16* dst; int K, N, tt;
  if (tid < 1024) {
    int which = tid >> 8; tt = tid & 255; K = 512; N = 512;
    src = (which == 0) ? Wq : (which == 1) ? Wk : (which == 2) ? Wv : Wo;
    dst = (which == 0) ? wqT : (which == 1) ? wkT : (which == 2) ? wvT : woT;
  } else if (tid < 2048) {
    tt = tid - 1024; K = 512; N = 2048; src = W1; dst = w1T;
  } else {
    tt = tid - 2048; K = 2048; N = 512; src = W2; dst = w2T;
  }
  int nx = N >> 5;
  int n0 = (tt % nx) * 32, k0 = (tt / nx) * 32;
  int tx = threadIdx.x & 31, ty = threadIdx.x >> 5;
#pragma unroll
  for (int i = 0; i < 4; i++) {
    int r = ty + i * 8;
    tile[r][tx] = src[(size_t)(k0 + r) * N + n0 + tx];
  }
  __syncthreads();
#pragma unroll
  for (int i = 0; i < 4; i++) {
    int r = ty + i * 8;
    dst[(size_t)(n0 + r) * K + k0 + tx] = (__bf16)tile[tx][r];
  }
}

// -------- async global->LDS 16B helper (wave-uniform lds base + lane*16) ----
__device__ __forceinline__ void gload16(const __bf16* g, __bf16* lds) {
  __builtin_amdgcn_global_load_lds(
      (const __attribute__((address_space(1))) void*)g,
      (__attribute__((address_space(3))) void*)lds, 16, 0, 0);
}

// ------- bf16 MFMA GEMM, 128x128 tile (for wide-N: FF1) --------------------
template <int EPI, int OBF16>
__global__ __launch_bounds__(256) void gemm_mfma128(const __bf16* __restrict__ A,
                                                    const __bf16* __restrict__ Bt,
                                                    const float* __restrict__ R,
                                                    void* __restrict__ Cout,
                                                    int M, int N, int K) {
  __shared__ __align__(16) __bf16 Als[128 * 64];
  __shared__ __align__(16) __bf16 Bls[128 * 64];
  int t = threadIdx.x;
  int bn = blockIdx.x, bm = blockIdx.y;
  int lane = t & 63, w = t >> 6;
  int wr = w >> 1, wc = w & 1;
  int m15 = lane & 15, q = lane >> 4;
  f32x4 acc[4][4] = {};
  for (int kt = 0; kt < K; kt += 64) {
    __syncthreads();
#pragma unroll
    for (int i = 0; i < 4; i++) {
      int rg = w * 32 + i * 8;
      int row = rg + (lane >> 3);
      int lcol = (lane & 7) * 8;
      gload16(A + (size_t)(bm * 128 + row) * K + kt + lcol, &Als[rg * 64]);
      gload16(Bt + (size_t)(bn * 128 + row) * K + kt + lcol, &Bls[rg * 64]);
    }
    __syncthreads();
#pragma unroll
    for (int ks = 0; ks < 2; ks++) {
      bf16x8 af[4], bfr[4];
#pragma unroll
      for (int mt = 0; mt < 4; mt++)
        af[mt] = *(const bf16x8*)&Als[(wr * 64 + mt * 16 + m15) * 64 + (ks * 4 + q) * 8];
#pragma unroll
      for (int nt = 0; nt < 4; nt++)
        bfr[nt] = *(const bf16x8*)&Bls[(wc * 64 + nt * 16 + m15) * 64 + (ks * 4 + q) * 8];
#pragma unroll
      for (int mt = 0; mt < 4; mt++)
#pragma unroll
        for (int nt = 0; nt < 4; nt++)
          acc[mt][nt] = __builtin_amdgcn_mfma_f32_16x16x32_bf16(af[mt], bfr[nt],
                                                                acc[mt][nt], 0, 0, 0);
    }
  }
#pragma unroll
  for (int mt = 0; mt < 4; mt++) {
#pragma unroll
    for (int nt = 0; nt < 4; nt++) {
      int gc = bn * 128 + wc * 64 + nt * 16 + m15;
#pragma unroll
      for (int r = 0; r < 4; r++) {
        int gr = bm * 128 + wr * 64 + mt * 16 + q * 4 + r;
        size_t off = (size_t)gr * N + gc;
        float v = acc[mt][nt][r];
        if (EPI == 1) v = gelu_f(v);
        if (EPI == 2) v += R[off];
        if (OBF16) ((__bf16*)Cout)[off] = (__bf16)v;
        else       ((float*)Cout)[off] = v;
      }
    }
  }
}

// ------- bf16 MFMA GEMM, 128x64 tile (for narrow-N: QKV/Wo/FF2 grid fill) --
template <int EPI, int OBF16>
__global__ __launch_bounds__(256) void gemm_mfma64(const __bf16* __restrict__ A,
                                                   const __bf16* __restrict__ Bt,
                                                   const float* __restrict__ R,
                                                   void* __restrict__ Cout,
                                                   int M, int N, int K) {
  __shared__ __align__(16) __bf16 Als[128 * 64];
  __shared__ __align__(16) __bf16 Bls[64 * 64];
  int t = threadIdx.x;
  int bn = blockIdx.x, bm = blockIdx.y;
  int lane = t & 63, w = t >> 6;
  int wr = w >> 1, wc = w & 1;
  int m15 = lane & 15, q = lane >> 4;
  f32x4 acc[4][2] = {};
  for (int kt = 0; kt < K; kt += 64) {
    __syncthreads();
#pragma unroll
    for (int i = 0; i < 4; i++) {
      int rg = w * 32 + i * 8;
      int row = rg + (lane >> 3);
      int lcol = (lane & 7) * 8;
      gload16(A + (size_t)(bm * 128 + row) * K + kt + lcol, &Als[rg * 64]);
    }
#pragma unroll
    for (int i = 0; i < 2; i++) {
      int rg = w * 16 + i * 8;
      int row = rg + (lane >> 3);
      int lcol = (lane & 7) * 8;
      gload16(Bt + (size_t)(bn * 64 + row) * K + kt + lcol, &Bls[rg * 64]);
    }
    __syncthreads();
#pragma unroll
    for (int ks = 0; ks < 2; ks++) {
      bf16x8 af[4], bfr[2];
#pragma unroll
      for (int mt = 0; mt < 4; mt++)
        af[mt] = *(const bf16x8*)&Als[(wr * 64 + mt * 16 + m15) * 64 + (ks * 4 + q) * 8];
#pragma unroll
      for (int nt = 0; nt < 2; nt++)
        bfr[nt] = *(const bf16x8*)&Bls[(wc * 32 + nt * 16 + m15) * 64 + (ks * 4 + q) * 8];
#pragma unroll
      for (int mt = 0; mt < 4; mt++)
#pragma unroll
        for (int nt = 0; nt < 2; nt++)
          acc[mt][nt] = __builtin_amdgcn_mfma_f32_16x16x32_bf16(af[mt], bfr[nt],
                                                                acc[mt][nt], 0, 0, 0);
    }
  }
#pragma unroll
  for (int mt = 0; mt < 4; mt++) {
#pragma unroll
    for (int nt = 0; nt < 2; nt++) {
      int gc = bn * 64 + wc * 32 + nt * 16 + m15;
#pragma unroll
      for (int r = 0; r < 4; r++) {
        int gr = bm * 128 + wr * 64 + mt * 16 + q * 4 + r;
        size_t off = (size_t)gr * N + gc;
        float v = acc[mt][nt][r];
        if (EPI == 1) v = gelu_f(v);
        if (EPI == 2) v += R[off];
        if (OBF16) ((__bf16*)Cout)[off] = (__bf16)v;
        else       ((float*)Cout)[off] = v;
      }
    }
  }
}

// -------- split fp32 -> bf16 hi + bf16 lo (exact residual) --------
__global__ __launch_bounds__(256) void split_bf16_kernel(const float* __restrict__ src,
                                                         __bf16* __restrict__ hi,
                                                         __bf16* __restrict__ lo) {
  int i = blockIdx.x * 256 + threadIdx.x;
  float4 v = ((const float4*)src)[i];
  float xs[4] = {v.x, v.y, v.z, v.w};
  bf16x4 hv, lv;
#pragma unroll
  for (int e = 0; e < 4; e++) {
    __bf16 h = (__bf16)xs[e];
    hv[e] = h;
    lv[e] = (__bf16)(xs[e] - (float)h);
  }
  *(bf16x4*)&hi[(size_t)i * 4] = hv;
  *(bf16x4*)&lo[(size_t)i * 4] = lv;
}

// ---- per-head transpose + split: qkv v-part -> vt[b,h][64][512] bf16 ------
__global__ __launch_bounds__(256) void vtrans_split_kernel(const float* __restrict__ qkv,
                                                           __bf16* __restrict__ vth,
                                                           __bf16* __restrict__ vtl) {
  __shared__ float tile[64 * 68];
  int tt = blockIdx.x, h = blockIdx.y, b = blockIdx.z;
  int t = threadIdx.x;
#pragma unroll
  for (int i = 0; i < 4; i++) {
    int lin = i * 256 + t, row = lin >> 4, c = (lin & 15) * 4;
    float4 x = *(const float4*)(qkv + ((size_t)(b * NN) + tt * 64 + row) * QKVS + 1024 + h * DHH + c);
    *(float4*)&tile[row * 68 + c] = x;
  }
  __syncthreads();
  int d = t >> 2, tb = (t & 3) * 16;
  float xs[16];
#pragma unroll
  for (int j = 0; j < 16; j++) xs[j] = tile[(tb + j) * 68 + d];
  bf16x8 h0, h1, l0, l1;
#pragma unroll
  for (int j = 0; j < 8; j++) {
    __bf16 a = (__bf16)xs[j];
    h0[j] = a; l0[j] = (__bf16)(xs[j] - (float)a);
    __bf16 bmv = (__bf16)xs[8 + j];
    h1[j] = bmv; l1[j] = (__bf16)(xs[8 + j] - (float)bmv);
  }
  size_t ob = ((size_t)(b * HH + h) * 64 + d) * NN + tt * 64 + tb;
  *(bf16x8*)(vth + ob) = h0; *(bf16x8*)(vth + ob + 8) = h1;
  *(bf16x8*)(vtl + ob) = l0; *(bf16x8*)(vtl + ob + 8) = l1;
}

// ============ kNN path A: MFMA score GEMM -> S (chunk-local, fp32) =========
// 64 q-rows per block (grid 8 x nbh): 48 MFMA per staged K-tile (2x the
// arithmetic intensity of the 32-row version), half the K re-reads.
__global__ __launch_bounds__(256) void knn_score_mfma(const float* __restrict__ q,
                                                      const __bf16* __restrict__ khi,
                                                      const __bf16* __restrict__ klo,
                                                      float* __restrict__ S,
                                                      int bh0) {
  __shared__ __bf16 Kls[2][128 * 72];        // hi / lo staging, stride 72
  int it = blockIdx.x, bh = bh0 + blockIdx.y;
  int b = bh >> 3, h = bh & 7;
  int t = threadIdx.x;
  int lane = t & 63, w = t >> 6;
  int m15 = lane & 15, kg = lane >> 4;
  const float scale = 0.125f;

  bf16x8 aqh[4][2], aql[4][2];
#pragma unroll
  for (int rf = 0; rf < 4; rf++)
#pragma unroll
    for (int ks = 0; ks < 2; ks++) {
      const float* qp = q + ((size_t)(b * NN) + it * 64 + rf * 16 + m15) * QKVS +
                        h * DHH + ks * 32 + kg * 8;
      float4 x0 = *(const float4*)qp;
      float4 x1 = *(const float4*)(qp + 4);
      float xs[8] = {x0.x, x0.y, x0.z, x0.w, x1.x, x1.y, x1.z, x1.w};
#pragma unroll
      for (int e = 0; e < 8; e++) {
        __bf16 hv = (__bf16)xs[e];
        aqh[rf][ks][e] = hv;
        aql[rf][ks][e] = (__bf16)(xs[e] - (float)hv);
      }
    }

  const __bf16* khb = khi + (size_t)b * MEMM * DHH;
  const __bf16* klb = klo + (size_t)b * MEMM * DHH;
  size_t srow0 = (size_t)blockIdx.y * NN + it * 64;  // chunk-local row base

  for (int mt = 0; mt < MEMM; mt += 128) {
    __syncthreads();
#pragma unroll
    for (int i = 0; i < 4; i++) {
      int lin = i * 256 + t;
      int row = lin >> 3, cb = (lin & 7) * 8;
      *(uint4*)&Kls[0][row * 72 + cb] = *(const uint4*)(khb + (size_t)(mt + row) * DHH + cb);
      *(uint4*)&Kls[1][row * 72 + cb] = *(const uint4*)(klb + (size_t)(mt + row) * DHH + cb);
    }
    __syncthreads();
    f32x4 acc[4][2] = {};
#pragma unroll
    for (int ks = 0; ks < 2; ks++) {
      bf16x8 bh2[2], bl2[2];
#pragma unroll
      for (int cf = 0; cf < 2; cf++) {
        int row = w * 32 + cf * 16 + m15;
        bh2[cf] = *(const bf16x8*)&Kls[0][row * 72 + ks * 32 + kg * 8];
        bl2[cf] = *(const bf16x8*)&Kls[1][row * 72 + ks * 32 + kg * 8];
      }
#pragma unroll
      for (int rf = 0; rf < 4; rf++)
#pragma unroll
        for (int cf = 0; cf < 2; cf++) {
          acc[rf][cf] = __builtin_amdgcn_mfma_f32_16x16x32_bf16(aqh[rf][ks], bh2[cf], acc[rf][cf], 0, 0, 0);
          acc[rf][cf] = __builtin_amdgcn_mfma_f32_16x16x32_bf16(aql[rf][ks], bh2[cf], acc[rf][cf], 0, 0, 0);
          acc[rf][cf] = __builtin_amdgcn_mfma_f32_16x16x32_bf16(aqh[rf][ks], bl2[cf], acc[rf][cf], 0, 0, 0);
        }
    }
#pragma unroll
    for (int rf = 0; rf < 4; rf++)
#pragma unroll
      for (int cf = 0; cf < 2; cf++) {
        int col = mt + w * 32 + cf * 16 + m15;
#pragma unroll
        for (int rr = 0; rr < 4; rr++)
          S[(srow0 + rf * 16 + kg * 4 + rr) * MEMM + col] = acc[rf][cf][rr] * scale;
      }
  }
}

// ============ kNN path B: exact top-32 per row via bit-serial radix =========
// Lane owns cands {i*256 + lane*4 + e}: 16 dwordx4 loads (1 KB/wave/instr).
// Count: 64 independent VALU adds + 6-step shuffle reduce (R6-measured form).
__global__ __launch_bounds__(256, 4) void knn_select_kernel(const float* __restrict__ S,
                                                            float* __restrict__ topv,
                                                            int* __restrict__ topi,
                                                            int row_base) {
  int lane = threadIdx.x & 63;
  int row = blockIdx.x * 4 + (threadIdx.x >> 6);
  const float* srow = S + (size_t)row * MEMM;
  unsigned u[64];
#pragma unroll
  for (int i = 0; i < 16; i++) {
    uint4 v = *(const uint4*)(srow + i * 256 + lane * 4);
    unsigned vs[4] = {v.x, v.y, v.z, v.w};
#pragma unroll
    for (int e = 0; e < 4; e++) {
      unsigned bb = vs[e];
      u[i * 4 + e] = (bb & 0x80000000u) ? ~bb : (bb | 0x80000000u);
    }
  }
  unsigned T = 0;
#pragma unroll 1
  for (int bit = 31; bit >= 0; --bit) {
    unsigned Tp = T | (1u << bit);
    int c = 0;
#pragma unroll
    for (int j = 0; j < 64; j++) c += (u[j] >= Tp) ? 1 : 0;
#pragma unroll
    for (int m = 32; m; m >>= 1) c += __shfl_xor(c, m, 64);
    if (c >= TOPKK) {
      T = Tp;
      if (c == TOPKK) break;
    }
  }
  unsigned long long below = (1ull << lane) - 1ull;
  float* tvrow = topv + (size_t)(row_base + row) * TOPKK;
  int* tirow = topi + (size_t)(row_base + row) * TOPKK;
  int g = 0;
#pragma unroll
  for (int i = 0; i < 16; i++)
#pragma unroll
    for (int e = 0; e < 4; e++) {
      int j = i * 4 + e;
      bool f = u[j] > T;
      unsigned long long m = __ballot(f);
      if (f) {
        int pos = g + __popcll(m & below);
        union { unsigned b; float f2; } rv;
        rv.b = (u[j] & 0x80000000u) ? (u[j] & 0x7fffffffu) : ~u[j];
        tvrow[pos] = rv.f2;
        tirow[pos] = i * 256 + lane * 4 + e;
      }
      g += __popcll(m);
    }
#pragma unroll 1
  for (int i = 0; i < 16 && g < TOPKK; i++)
#pragma unroll
    for (int e = 0; e < 4; e++) {
      int j = i * 4 + e;
      bool f = (u[j] == T);
      unsigned long long m = __ballot(f);
      if (f) {
        int pos = g + __popcll(m & below);
        if (pos < TOPKK) {
          union { unsigned b; float f2; } rv;
          rv.b = (T & 0x80000000u) ? (T & 0x7fffffffu) : ~T;
          tvrow[pos] = rv.f2;
          tirow[pos] = i * 256 + lane * 4 + e;
        }
      }
      g += __popcll(m);
    }
}

// ---------------- top-32 insert helper (fused fallback only) ----------------
__device__ __forceinline__ void insert32vi(float (&rtv)[32], int (&rti)[32],
                                           float sv, int idx, float& thr) {
  float mv = rtv[0], mv2 = INFINITY;
  int mi = 0;
#pragma unroll
  for (int k = 1; k < 32; k++) {
    float v = rtv[k];
    bool lt = v < mv;
    mv2 = lt ? mv : fminf(mv2, v);
    mv = lt ? v : mv;
    mi = lt ? k : mi;
  }
#pragma unroll
  for (int k = 0; k < 32; k++) {
    bool hit = (k == mi);
    rtv[k] = hit ? sv : rtv[k];
    rti[k] = hit ? idx : rti[k];
  }
  thr = fminf(mv2, sv);
}

// ============ fused MFMA score GEMM + top-32 (FALLBACK, tiny ws) ===========
__global__ __launch_bounds__(256) void knn_mfma_topk(const float* __restrict__ q,
                                                     const __bf16* __restrict__ khi,
                                                     const __bf16* __restrict__ klo,
                                                     float* __restrict__ topv,
                                                     int* __restrict__ topi) {
  __shared__ __bf16 Kls[2][128 * 72];
  __shared__ float scb[32][132];
  __shared__ unsigned short midx[32 * 260];
  __shared__ float rthr[8][32];
  int it = blockIdx.x, h = blockIdx.y, b = blockIdx.z;
  int t = threadIdx.x;
  int lane = t & 63, w = t >> 6;
  int m15 = lane & 15, kg = lane >> 4;
  const float scale = 0.125f;
  bf16x8 aqh[2][2], aql[2][2];
#pragma unroll
  for (int rf = 0; rf < 2; rf++)
#pragma unroll
    for (int ks = 0; ks < 2; ks++) {
      const float* qp = q + ((size_t)(b * NN) + it * 32 + rf * 16 + m15) * QKVS +
                        h * DHH + ks * 32 + kg * 8;
      float4 x0 = *(const float4*)qp;
      float4 x1 = *(const float4*)(qp + 4);
      float xs[8] = {x0.x, x0.y, x0.z, x0.w, x1.x, x1.y, x1.z, x1.w};
#pragma unroll
      for (int e = 0; e < 8; e++) {
        __bf16 hv = (__bf16)xs[e];
        aqh[rf][ks][e] = hv;
        aql[rf][ks][e] = (__bf16)(xs[e] - (float)hv);
      }
    }
  int r = t & 31, p = t >> 5;
  rthr[p][r] = -INFINITY;
  float rtv[32]; int rti[32];
#pragma unroll
  for (int k = 0; k < 32; k++) { rtv[k] = -INFINITY; rti[k] = 0; }
  float thr = -INFINITY;
  const __bf16* khb = khi + (size_t)b * MEMM * DHH;
  const __bf16* klb = klo + (size_t)b * MEMM * DHH;

  for (int mt = 0; mt < MEMM; mt += 128) {
    __syncthreads();
#pragma unroll
    for (int i = 0; i < 4; i++) {
      int lin = i * 256 + t;
      int row = lin >> 3, cb = (lin & 7) * 8;
      *(uint4*)&Kls[0][row * 72 + cb] = *(const uint4*)(khb + (size_t)(mt + row) * DHH + cb);
      *(uint4*)&Kls[1][row * 72 + cb] = *(const uint4*)(klb + (size_t)(mt + row) * DHH + cb);
    }
    __syncthreads();
    f32x4 acc[2][2] = {};
#pragma unroll
    for (int ks = 0; ks < 2; ks++) {
      bf16x8 bh2[2], bl2[2];
#pragma unroll
      for (int cf = 0; cf < 2; cf++) {
        int row = w * 32 + cf * 16 + m15;
        bh2[cf] = *(const bf16x8*)&Kls[0][row * 72 + ks * 32 + kg * 8];
        bl2[cf] = *(const bf16x8*)&Kls[1][row * 72 + ks * 32 + kg * 8];
      }
#pragma unroll
      for (int rf = 0; rf < 2; rf++)
#pragma unroll
        for (int cf = 0; cf < 2; cf++) {
          acc[rf][cf] = __builtin_amdgcn_mfma_f32_16x16x32_bf16(aqh[rf][ks], bh2[cf], acc[rf][cf], 0, 0, 0);
          acc[rf][cf] = __builtin_amdgcn_mfma_f32_16x16x32_bf16(aql[rf][ks], bh2[cf], acc[rf][cf], 0, 0, 0);
          acc[rf][cf] = __builtin_amdgcn_mfma_f32_16x16x32_bf16(aqh[rf][ks], bl2[cf], acc[rf][cf], 0, 0, 0);
        }
    }
#pragma unroll
    for (int rf = 0; rf < 2; rf++)
#pragma unroll
      for (int cf = 0; cf < 2; cf++) {
        int col = w * 32 + cf * 16 + m15;
#pragma unroll
        for (int rr = 0; rr < 4; rr++)
          scb[rf * 16 + kg * 4 + rr][col] = acc[rf][cf][rr] * scale;
      }
    __syncthreads();
    {
      float B2 = rthr[0][r];
#pragma unroll
      for (int j = 1; j < 8; j++) B2 = fmaxf(B2, rthr[j][r]);
      const float* srow = &scb[r][16 * p];
#pragma unroll 1
      for (int c = 0; c < 16; c++) {
        int cc = (c + r) & 15;
        float sv = srow[cc];
        if (sv > fmaxf(thr, B2))
          insert32vi(rtv, rti, sv, mt + 16 * p + cc, thr);
      }
      rthr[p][r] = thr;
    }
  }
  __syncthreads();
  float* mvals = (float*)&Kls[0][0];
#pragma unroll
  for (int k = 0; k < 32; k++) {
    int cc = (k + r) & 31;
    mvals[(size_t)260 * r + 32 * p + cc] = rtv[k];
    midx[(size_t)260 * r + 32 * p + cc] = (unsigned short)rti[k];
  }
  __syncthreads();
  if (t < 32) {
#pragma unroll 1
    for (int c = 0; c < 224; c++) {
      int cc = c + r; if (cc >= 224) cc -= 224;
      float sv = mvals[(size_t)260 * r + 32 + cc];
      if (sv > thr)
        insert32vi(rtv, rti, sv, (int)midx[(size_t)260 * r + 32 + cc], thr);
    }
    size_t rowg = ((size_t)b * HH + h) * NN + it * 32 + r;
#pragma unroll
    for (int k = 0; k < 32; k++) {
      topv[rowg * TOPKK + k] = rtv[k];
      topi[rowg * TOPKK + k] = rti[k];
    }
  }
}

// ======== MFMA flash attention (compensated bf16, swapped QK^T layout) =====
// 1-D grid 512: flat = bi*64 + (b*8+h) -> blocks of one (b,h) co-locate on
// one XCD (L2 reuse of K/V). K/V tile jt+1 prefetched to regs (T14).
__global__ __launch_bounds__(256) void attn_mfma_kernel(
    const float* __restrict__ qkv,
    const __bf16* __restrict__ vth, const __bf16* __restrict__ vtl,
    __bf16* __restrict__ ao, const float* __restrict__ topv,
    const int* __restrict__ topi, const float* __restrict__ mem_v, int knn) {
  __shared__ __align__(16) __bf16 smem[27648];   // 55296 B
  __bf16* Kh = smem;                 // [64][72]
  __bf16* Kl = smem + 4608;
  __bf16* Vh = smem + 9216;          // V^T [d 64][72]
  __bf16* Vl = smem + 13824;
  __bf16* Pw = smem + 18432;         // [wave][hi/lo][16][72]

  int flat = blockIdx.x;
  int bi = flat >> 6;
  int hb = flat & 63;
  int h = hb & 7, b = hb >> 3;
  int t = threadIdx.x, lane = t & 63, w = t >> 6;
  int q15 = lane & 15, g = lane >> 4;
  const float scale = 0.125f;

  bf16x8 qh[2], ql[2];
  {
    const float* qp = qkv + ((size_t)(b * NN) + bi * 64 + w * 16 + q15) * QKVS + h * DHH;
#pragma unroll
    for (int ks = 0; ks < 2; ks++) {
      float4 x0 = *(const float4*)(qp + ks * 32 + g * 8);
      float4 x1 = *(const float4*)(qp + ks * 32 + g * 8 + 4);
      float xs[8] = {x0.x, x0.y, x0.z, x0.w, x1.x, x1.y, x1.z, x1.w};
#pragma unroll
      for (int e = 0; e < 8; e++) {
        __bf16 hv = (__bf16)xs[e];
        qh[ks][e] = hv;
        ql[ks][e] = (__bf16)(xs[e] - (float)hv);
      }
    }
  }
  int tr = t >> 4, kc = (t & 15) * 4;      // K: rows tr, tr+16, tr+32, tr+48
  int td = t >> 3, tb = (t & 7) * 8;       // V: rows td, td+32
  float4 kp0, kp1, kp2, kp3;
  uint4 vhp0, vhp1, vlp0, vlp1;

#define LOAD_TILE(jt_) do {                                                        \
    const float* kb_ = qkv + ((size_t)(b * NN) + (jt_) * 64 + tr) * QKVS + 512 +   \
                       h * DHH + kc;                                               \
    kp0 = *(const float4*)kb_;                                                     \
    kp1 = *(const float4*)(kb_ + (size_t)16 * QKVS);                               \
    kp2 = *(const float4*)(kb_ + (size_t)32 * QKVS);                               \
    kp3 = *(const float4*)(kb_ + (size_t)48 * QKVS);                               \
    size_t vb_ = ((size_t)(b * HH + h) * 64 + td) * NN + (jt_) * 64 + tb;          \
    vhp0 = *(const uint4*)(vth + vb_);                                             \
    vhp1 = *(const uint4*)(vth + vb_ + (size_t)32 * NN);                           \
    vlp0 = *(const uint4*)(vtl + vb_);                                             \
    vlp1 = *(const uint4*)(vtl + vb_ + (size_t)32 * NN);                           \
  } while (0)

#define STORE_K(kp_, ro_) do {                                                     \
    bf16x4 hv_, lv_;                                                               \
    float e0_ = kp_.x, e1_ = kp_.y, e2_ = kp_.z, e3_ = kp_.w;                      \
    hv_[0] = (__bf16)e0_; lv_[0] = (__bf16)(e0_ - (float)hv_[0]);                  \
    hv_[1] = (__bf16)e1_; lv_[1] = (__bf16)(e1_ - (float)hv_[1]);                  \
    hv_[2] = (__bf16)e2_; lv_[2] = (__bf16)(e2_ - (float)hv_[2]);                  \
    hv_[3] = (__bf16)e3_; lv_[3] = (__bf16)(e3_ - (float)hv_[3]);                  \
    *(bf16x4*)&Kh[((ro_) + tr) * 72 + kc] = hv_;                                   \
    *(bf16x4*)&Kl[((ro_) + tr) * 72 + kc] = lv_;                                   \
  } while (0)

  float m_run = -INFINITY, l_run = 0.f;
  f32x4 opv[4] = {};
  int ntiles = bi + 1;
  LOAD_TILE(0);
  for (int jt = 0; jt < ntiles; jt++) {
    __syncthreads();
    STORE_K(kp0, 0); STORE_K(kp1, 16); STORE_K(kp2, 32); STORE_K(kp3, 48);
    *(uint4*)&Vh[td * 72 + tb] = vhp0;
    *(uint4*)&Vh[(32 + td) * 72 + tb] = vhp1;
    *(uint4*)&Vl[td * 72 + tb] = vlp0;
    *(uint4*)&Vl[(32 + td) * 72 + tb] = vlp1;
    if (jt + 1 < ntiles) LOAD_TILE(jt + 1);
    __syncthreads();
    int smax = (jt == bi) ? w : 3;
    float sc16[16];
    float tmax = -INFINITY;
#pragma unroll
    for (int s = 0; s < 4; s++) {
      if (s <= smax) {
        f32x4 accs = {};
#pragma unroll
        for (int ks = 0; ks < 2; ks++) {
          bf16x8 ah = *(const bf16x8*)&Kh[(s * 16 + q15) * 72 + ks * 32 + g * 8];
          bf16x8 al = *(const bf16x8*)&Kl[(s * 16 + q15) * 72 + ks * 32 + g * 8];
          accs = __builtin_amdgcn_mfma_f32_16x16x32_bf16(ah, qh[ks], accs, 0, 0, 0);
          accs = __builtin_amdgcn_mfma_f32_16x16x32_bf16(al, qh[ks], accs, 0, 0, 0);
          accs = __builtin_amdgcn_mfma_f32_16x16x32_bf16(ah, ql[ks], accs, 0, 0, 0);
        }
#pragma unroll
        for (int r = 0; r < 4; r++) {
          float sv = accs[r] * scale;
          if (jt == bi) {
            int kvg = jt * 64 + s * 16 + g * 4 + r;
            int qg = bi * 64 + w * 16 + q15;
            if (kvg > qg) sv = -INFINITY;
          }
          sc16[s * 4 + r] = sv;
          tmax = fmaxf(tmax, sv);
        }
      } else {
#pragma unroll
        for (int r = 0; r < 4; r++) sc16[s * 4 + r] = -INFINITY;
      }
    }
    tmax = fmaxf(tmax, __shfl_xor(tmax, 16, 64));
    tmax = fmaxf(tmax, __shfl_xor(tmax, 32, 64));
    float m_new = fmaxf(m_run, tmax);
    float psum = 0.f;
    __bf16 ph[16], pl[16];
#pragma unroll
    for (int i = 0; i < 16; i++) {
      float p = __expf(sc16[i] - m_new);
      psum += p;
      __bf16 hp = (__bf16)p;
      ph[i] = hp; pl[i] = (__bf16)(p - (float)hp);
    }
    psum += __shfl_xor(psum, 16, 64);
    psum += __shfl_xor(psum, 32, 64);
    float alpha = __expf(m_run - m_new);
    l_run = l_run * alpha + psum;
    m_run = m_new;
    __bf16* Ph = Pw + (w * 2 + 0) * 1152;
    __bf16* Pl = Pw + (w * 2 + 1) * 1152;
#pragma unroll
    for (int s = 0; s < 4; s++) {
      bf16x4 hv, lv;
#pragma unroll
      for (int r = 0; r < 4; r++) { hv[r] = ph[s * 4 + r]; lv[r] = pl[s * 4 + r]; }
      *(bf16x4*)&Ph[q15 * 72 + s * 16 + g * 4] = hv;
      *(bf16x4*)&Pl[q15 * 72 + s * 16 + g * 4] = lv;
    }
    __builtin_amdgcn_wave_barrier();
    float a0 = __shfl(alpha, g * 4 + 0, 64);
    float a1 = __shfl(alpha, g * 4 + 1, 64);
    float a2 = __shfl(alpha, g * 4 + 2, 64);
    float a3 = __shfl(alpha, g * 4 + 3, 64);
#pragma unroll
    for (int dsub = 0; dsub < 4; dsub++) {
      opv[dsub][0] *= a0; opv[dsub][1] *= a1;
      opv[dsub][2] *= a2; opv[dsub][3] *= a3;
    }
#pragma unroll
    for (int ks2 = 0; ks2 < 2; ks2++) {
      bf16x8 pah = *(const bf16x8*)&Ph[q15 * 72 + ks2 * 32 + g * 8];
      bf16x8 pal = *(const bf16x8*)&Pl[q15 * 72 + ks2 * 32 + g * 8];
#pragma unroll
      for (int dsub = 0; dsub < 4; dsub++) {
        bf16x8 vbh = *(const bf16x8*)&Vh[(dsub * 16 + q15) * 72 + ks2 * 32 + g * 8];
        bf16x8 vbl = *(const bf16x8*)&Vl[(dsub * 16 + q15) * 72 + ks2 * 32 + g * 8];
        opv[dsub] = __builtin_amdgcn_mfma_f32_16x16x32_bf16(pah, vbh, opv[dsub], 0, 0, 0);
        opv[dsub] = __builtin_amdgcn_mfma_f32_16x16x32_bf16(pal, vbh, opv[dsub], 0, 0, 0);
        opv[dsub] = __builtin_amdgcn_mfma_f32_16x16x32_bf16(pah, vbl, opv[dsub], 0, 0, 0);
      }
    }
  }
#undef LOAD_TILE
#undef STORE_K
  __syncthreads();
  float* scf  = (float*)smem;                 // [64][68] fp32
  float* marr = (float*)(smem + 8704);
  float* larr = marr + 64;
  float* aarr = marr + 128;
  float* sc2  = (float*)(smem + 9216);        // [64][33] fp32
  int*   pidx = (int*)(smem + 13824);         // [64][32] int
#pragma unroll
  for (int dsub = 0; dsub < 4; dsub++)
#pragma unroll
    for (int r = 0; r < 4; r++)
      scf[(w * 16 + g * 4 + r) * 68 + dsub * 16 + q15] = opv[dsub][r];
  if (g == 0) { marr[w * 16 + q15] = m_run; larr[w * 16 + q15] = l_run; }
  __syncthreads();
  int r_ = t & 63, w4 = t >> 6;
  float acc16[16];
  if (knn) {
    size_t rowbase = ((size_t)b * HH + h) * NN + bi * 64;
    for (int rr = w * 16; rr < w * 16 + 16; rr++) {
      float s = (lane < TOPKK) ? topv[(rowbase + rr) * TOPKK + lane] : -INFINITY;
      float m_old = marr[rr];
      float tm = s;
#pragma unroll
      for (int m = 32; m; m >>= 1) tm = fmaxf(tm, __shfl_xor(tm, m, 64));
      float m_new = fmaxf(m_old, tm);
      float p = __expf(s - m_new);
      float ts = p;
#pragma unroll
      for (int m = 32; m; m >>= 1) ts += __shfl_xor(ts, m, 64);
      float alpha = __expf(m_old - m_new);
      if (lane < TOPKK) {
        sc2[rr * 33 + lane] = p;
        pidx[rr * 32 + lane] = topi[(rowbase + rr) * TOPKK + lane];
      }
      if (lane == 0) {
        marr[rr] = m_new; larr[rr] = larr[rr] * alpha + ts; aarr[rr] = alpha;
      }
    }
    __syncthreads();
    float al = aarr[r_];
#pragma unroll
    for (int dd = 0; dd < 16; dd++) acc16[dd] = scf[r_ * 68 + w4 * 16 + dd] * al;
    const float* mvb = mem_v + (size_t)b * MEMM * DHH;
#pragma unroll 1
    for (int kk = 0; kk < TOPKK; kk++) {
      float p = sc2[r_ * 33 + kk];
      const float* mrow = mvb + (size_t)pidx[r_ * 32 + kk] * DHH + w4 * 16;
#pragma unroll
      for (int dd = 0; dd < 16; dd += 4) {
        float4 m4 = *(const float4*)(mrow + dd);
        acc16[dd] += p * m4.x; acc16[dd + 1] += p * m4.y;
        acc16[dd + 2] += p * m4.z; acc16[dd + 3] += p * m4.w;
      }
    }
  } else {
#pragma unroll
    for (int dd = 0; dd < 16; dd++) acc16[dd] = scf[r_ * 68 + w4 * 16 + dd];
  }
  float linv = 1.f / larr[r_];
  bf16x8 o0, o1;
#pragma unroll
  for (int j = 0; j < 8; j++) {
    o0[j] = (__bf16)(acc16[j] * linv);
    o1[j] = (__bf16)(acc16[8 + j] * linv);
  }
  __bf16* aop = ao + ((size_t)(b * NN) + bi * 64 + r_) * DD + h * DHH + w4 * 16;
  *(bf16x8*)aop = o0;
  *(bf16x8*)(aop + 8) = o1;
}

// ---------------- host ----------------
extern "C" void kernel_launch(void* const* d_in, const int* in_sizes, int n_in,
                              void* d_out, int out_size, void* d_ws, size_t ws_size,
                              hipStream_t stream) {
  const float* x_in  = (const float*)d_in[0];
  const float* Wq    = (const float*)d_in[1];
  const float* Wk    = (const float*)d_in[2];
  const float* Wv    = (const float*)d_in[3];
  const float* Wo    = (const float*)d_in[4];
  const float* ln1_s = (const float*)d_in[5];
  const float* ln1_b = (const float*)d_in[6];
  const float* ln2_s = (const float*)d_in[7];
  const float* ln2_b = (const float*)d_in[8];
  const float* W1    = (const float*)d_in[9];
  const float* W2    = (const float*)d_in[10];
  const float* lnf_s = (const float*)d_in[11];
  const float* lnf_b = (const float*)d_in[12];
  const float* mem_k = (const float*)d_in[13];
  const float* mem_v = (const float*)d_in[14];

  float* ws  = (float*)d_ws;
  float*  xb    = ws;
  float*  qkvb  = ws + 2097152;           // [4096][1536] fp32
  __bf16* hb16  = (__bf16*)(ws + 8388608);
  __bf16* ao16  = (__bf16*)(ws + 9437184);
  __bf16* wqT   = (__bf16*)(ws + 10485760);   // wq/wk/wv contiguous [1536][512]
  __bf16* woT   = (__bf16*)(ws + 10878976);
  __bf16* w1T   = (__bf16*)(ws + 11010048);
  __bf16* w2T   = (__bf16*)(ws + 11534336);
  float*  tvb   = ws + 12058624;
  int*    tib   = (int*)(ws + 13107200);
  __bf16* ffb16 = (__bf16*)(ws + 2097152);    // aliases qkvb (dead post-attn)
  __bf16* wkT   = wqT + 262144;
  __bf16* wvT   = wqT + 524288;
  __bf16* khi16 = (__bf16*)(ws + 8388608);
  __bf16* klo16 = (__bf16*)(ws + 9437184);

  // S chunk region after base layout; V^T hi/lo overlap it (lifetime-disjoint).
  // ws only fits nbh=16 in practice (R6/R7 FETCH evidence) — search is kept
  // for robustness on larger workspaces.
  const size_t base_floats = 14155776;
  const size_t slice_floats = (size_t)NN * MEMM;
  const size_t ws_floats = ws_size / sizeof(float);
  int nbh = 0;
  for (int c = 64; c >= 1; c >>= 1) {
    if (base_floats + (size_t)c * slice_floats <= ws_floats) { nbh = c; break; }
  }
  float* Sb = ws + base_floats;
  __bf16* vth = (__bf16*)(ws + base_floats);
  __bf16* vtl = (__bf16*)(ws + base_floats + 1048576);

  dim3 blk(256);
  const size_t DD2 = (size_t)DD * DD;
  for (int l = 0; l < DEPTHH; l++) {
    const float* xcur = (l == 0) ? x_in : xb;
    transpose_all_kernel<<<dim3(3072), blk, 0, stream>>>(
        Wq + l * DD2, Wk + l * DD2, Wv + l * DD2, Wo + l * DD2,
        W1 + (size_t)l * DD * FFF, W2 + (size_t)l * FFF * DD,
        wqT, wkT, wvT, woT, w1T, w2T);

    ln_kernel<1><<<NT, blk, 0, stream>>>(xcur, ln1_s + l * DD, ln1_b + l * DD, hb16);
    gemm_mfma64<0, 0><<<dim3(24, 32), blk, 0, stream>>>(hb16, wqT, nullptr, qkvb, NT, QKVS, DD);
    int mi = (l == 3) ? 0 : ((l == 4) ? 1 : -1);
    if (mi >= 0) {
      const float* mk = mem_k + (size_t)mi * BB * MEMM * DHH;
      split_bf16_kernel<<<dim3(BB * MEMM * DHH / 1024), blk, 0, stream>>>(mk, khi16, klo16);
      if (nbh > 0) {
        for (int bh0 = 0; bh0 < BB * HH; bh0 += nbh) {
          knn_score_mfma<<<dim3(8, nbh), blk, 0, stream>>>(qkvb, khi16, klo16, Sb, bh0);
          knn_select_kernel<<<dim3(nbh * NN / 4), blk, 0, stream>>>(Sb, tvb, tib, bh0 * NN);
        }
      } else {
        knn_mfma_topk<<<dim3(16, 8, 8), blk, 0, stream>>>(qkvb, khi16, klo16, tvb, tib);
      }
    }
    vtrans_split_kernel<<<dim3(8, 8, 8), blk, 0, stream>>>(qkvb, vth, vtl);
    attn_mfma_kernel<<<dim3(512), blk, 0, stream>>>(
        qkvb, vth, vtl, ao16, tvb, tib,
        mem_v + (size_t)(mi < 0 ? 0 : mi) * BB * MEMM * DHH, mi >= 0 ? 1 : 0);
    gemm_mfma64<2, 0><<<dim3(8, 32), blk, 0, stream>>>(ao16, woT, xcur, xb, NT, DD, DD);
    ln_kernel<1><<<NT, blk, 0, stream>>>(xb, ln2_s + l * DD, ln2_b + l * DD, hb16);
    gemm_mfma128<1, 1><<<dim3(16, 32), blk, 0, stream>>>(hb16, w1T, nullptr, ffb16, NT, FFF, DD);
    gemm_mfma64<2, 0><<<dim3(8, 32), blk, 0, stream>>>(ffb16, w2T, xb, xb, NT, DD, FFF);
  }
  ln_kernel<0><<<NT, blk, 0, stream>>>(xb, lnf_s, lnf_b, (float*)d_out);
}

// Round 9
// 1974.913 us; speedup vs baseline: 1.0790x; 1.0790x over previous
//
#include <hip/hip_runtime.h>
#include <math.h>

#define BB 8
#define NN 512
#define DD 512
#define HH 8
#define DHH 64
#define FFF 2048
#define MEMM 4096
#define TOPKK 32
#define DEPTHH 6
#define NT (BB*NN)   /* 4096 tokens */
#define QKVS 1536    /* fused qkv row stride */

typedef __bf16 bf16x8 __attribute__((ext_vector_type(8)));
typedef __bf16 bf16x4 __attribute__((ext_vector_type(4)));
typedef float f32x4 __attribute__((ext_vector_type(4)));

// ---------------- LayerNorm (fp32 in, fp32 or bf16 out) ----------------
template <int OBF16>
__global__ __launch_bounds__(256) void ln_kernel(const float* __restrict__ xin,
                                                 const float* __restrict__ g,
                                                 const float* __restrict__ bt,
                                                 void* __restrict__ outv) {
  __shared__ float red[4];
  int tok = blockIdx.x;
  const float* xr = xin + (size_t)tok * DD;
  int t = threadIdx.x;
  float v0 = xr[t], v1 = xr[t + 256];
  float s = v0 + v1;
#pragma unroll
  for (int m = 32; m; m >>= 1) s += __shfl_xor(s, m, 64);
  if ((t & 63) == 0) red[t >> 6] = s;
  __syncthreads();
  float mean = (red[0] + red[1] + red[2] + red[3]) * (1.0f / 512.0f);
  float d0 = v0 - mean, d1 = v1 - mean;
  float vv = d0 * d0 + d1 * d1;
#pragma unroll
  for (int m = 32; m; m >>= 1) vv += __shfl_xor(vv, m, 64);
  __syncthreads();
  if ((t & 63) == 0) red[t >> 6] = vv;
  __syncthreads();
  float var = (red[0] + red[1] + red[2] + red[3]) * (1.0f / 512.0f);
  float inv = rsqrtf(var + 1e-5f);
  float o0 = d0 * inv * g[t] + bt[t];
  float o1 = d1 * inv * g[t + 256] + bt[t + 256];
  if (OBF16) {
    __bf16* out = (__bf16*)outv;
    out[(size_t)tok * DD + t] = (__bf16)o0;
    out[(size_t)tok * DD + t + 256] = (__bf16)o1;
  } else {
    float* out = (float*)outv;
    out[(size_t)tok * DD + t] = o0;
    out[(size_t)tok * DD + t + 256] = o1;
  }
}

__device__ inline float gelu_f(float x) {
  float x3 = x * x * x;
  return 0.5f * x * (1.0f + tanhf(0.7978845608028654f * (x + 0.044715f * x3)));
}

// --------- batched weight transpose+convert: all 6 weights, one launch ------
__global__ __launch_bounds__(256) void transpose_all_kernel(
    const float* __restrict__ Wq, const float* __restrict__ Wk,
    const float* __restrict__ Wv, const float* __restrict__ Wo,
    const float* __restrict__ W1, const float* __restrict__ W2,
    __bf16* __restrict__ wqT, __bf16* __restrict__ wkT,
    __bf16* __restrict__ wvT, __bf16* __restrict__ woT,
    __bf16* __restrict__ w1T, __bf16* __restrict__ w2T) {
  __shared__ float tile[32][33];
  int tid = blockIdx.x;
  const float* src; __bf16* dst; int K, N, tt;
  if (tid < 1024) {
    int which = tid >> 8; tt = tid & 255; K = 512; N = 512;
    src = (which == 0) ? Wq : (which == 1) ? Wk : (which == 2) ? Wv : Wo;
    dst = (which == 0) ? wqT : (which == 1) ? wkT : (which == 2) ? wvT : woT;
  } else if (tid < 2048) {
    tt = tid - 1024; K = 512; N = 2048; src = W1; dst = w1T;
  } else {
    tt = tid - 2048; K = 2048; N = 512; src = W2; dst = w2T;
  }
  int nx = N >> 5;
  int n0 = (tt % nx) * 32, k0 = (tt / nx) * 32;
  int tx = threadIdx.x & 31, ty = threadIdx.x >> 5;
#pragma unroll
  for (int i = 0; i < 4; i++) {
    int r = ty + i * 8;
    tile[r][tx] = src[(size_t)(k0 + r) * N + n0 + tx];
  }
  __syncthreads();
#pragma unroll
  for (int i = 0; i < 4; i++) {
    int r = ty + i * 8;
    dst[(size_t)(n0 + r) * K + k0 + tx] = (__bf16)tile[tx][r];
  }
}

// -------- async global->LDS 16B helper (wave-uniform lds base + lane*16) ----
__device__ __forceinline__ void gload16(const __bf16* g, __bf16* lds) {
  __builtin_amdgcn_global_load_lds(
      (const __attribute__((address_space(1))) void*)g,
      (__attribute__((address_space(3))) void*)lds, 16, 0, 0);
}

// ------- bf16 MFMA GEMM, 128x128 tile (for wide-N: FF1) --------------------
template <int EPI, int OBF16>
__global__ __launch_bounds__(256) void gemm_mfma128(const __bf16* __restrict__ A,
                                                    const __bf16* __restrict__ Bt,
                                                    const float* __restrict__ R,
                                                    void* __restrict__ Cout,
                                                    int M, int N, int K) {
  __shared__ __align__(16) __bf16 Als[128 * 64];
  __shared__ __align__(16) __bf16 Bls[128 * 64];
  int t = threadIdx.x;
  int bn = blockIdx.x, bm = blockIdx.y;
  int lane = t & 63, w = t >> 6;
  int wr = w >> 1, wc = w & 1;
  int m15 = lane & 15, q = lane >> 4;
  f32x4 acc[4][4] = {};
  for (int kt = 0; kt < K; kt += 64) {
    __syncthreads();
#pragma unroll
    for (int i = 0; i < 4; i++) {
      int rg = w * 32 + i * 8;
      int row = rg + (lane >> 3);
      int lcol = (lane & 7) * 8;
      gload16(A + (size_t)(bm * 128 + row) * K + kt + lcol, &Als[rg * 64]);
      gload16(Bt + (size_t)(bn * 128 + row) * K + kt + lcol, &Bls[rg * 64]);
    }
    __syncthreads();
#pragma unroll
    for (int ks = 0; ks < 2; ks++) {
      bf16x8 af[4], bfr[4];
#pragma unroll
      for (int mt = 0; mt < 4; mt++)
        af[mt] = *(const bf16x8*)&Als[(wr * 64 + mt * 16 + m15) * 64 + (ks * 4 + q) * 8];
#pragma unroll
      for (int nt = 0; nt < 4; nt++)
        bfr[nt] = *(const bf16x8*)&Bls[(wc * 64 + nt * 16 + m15) * 64 + (ks * 4 + q) * 8];
#pragma unroll
      for (int mt = 0; mt < 4; mt++)
#pragma unroll
        for (int nt = 0; nt < 4; nt++)
          acc[mt][nt] = __builtin_amdgcn_mfma_f32_16x16x32_bf16(af[mt], bfr[nt],
                                                                acc[mt][nt], 0, 0, 0);
    }
  }
#pragma unroll
  for (int mt = 0; mt < 4; mt++) {
#pragma unroll
    for (int nt = 0; nt < 4; nt++) {
      int gc = bn * 128 + wc * 64 + nt * 16 + m15;
#pragma unroll
      for (int r = 0; r < 4; r++) {
        int gr = bm * 128 + wr * 64 + mt * 16 + q * 4 + r;
        size_t off = (size_t)gr * N + gc;
        float v = acc[mt][nt][r];
        if (EPI == 1) v = gelu_f(v);
        if (EPI == 2) v += R[off];
        if (OBF16) ((__bf16*)Cout)[off] = (__bf16)v;
        else       ((float*)Cout)[off] = v;
      }
    }
  }
}

// ------- bf16 MFMA GEMM, 128x64 tile (for narrow-N: QKV/Wo/FF2 grid fill) --
template <int EPI, int OBF16>
__global__ __launch_bounds__(256) void gemm_mfma64(const __bf16* __restrict__ A,
                                                   const __bf16* __restrict__ Bt,
                                                   const float* __restrict__ R,
                                                   void* __restrict__ Cout,
                                                   int M, int N, int K) {
  __shared__ __align__(16) __bf16 Als[128 * 64];
  __shared__ __align__(16) __bf16 Bls[64 * 64];
  int t = threadIdx.x;
  int bn = blockIdx.x, bm = blockIdx.y;
  int lane = t & 63, w = t >> 6;
  int wr = w >> 1, wc = w & 1;
  int m15 = lane & 15, q = lane >> 4;
  f32x4 acc[4][2] = {};
  for (int kt = 0; kt < K; kt += 64) {
    __syncthreads();
#pragma unroll
    for (int i = 0; i < 4; i++) {
      int rg = w * 32 + i * 8;
      int row = rg + (lane >> 3);
      int lcol = (lane & 7) * 8;
      gload16(A + (size_t)(bm * 128 + row) * K + kt + lcol, &Als[rg * 64]);
    }
#pragma unroll
    for (int i = 0; i < 2; i++) {
      int rg = w * 16 + i * 8;
      int row = rg + (lane >> 3);
      int lcol = (lane & 7) * 8;
      gload16(Bt + (size_t)(bn * 64 + row) * K + kt + lcol, &Bls[rg * 64]);
    }
    __syncthreads();
#pragma unroll
    for (int ks = 0; ks < 2; ks++) {
      bf16x8 af[4], bfr[2];
#pragma unroll
      for (int mt = 0; mt < 4; mt++)
        af[mt] = *(const bf16x8*)&Als[(wr * 64 + mt * 16 + m15) * 64 + (ks * 4 + q) * 8];
#pragma unroll
      for (int nt = 0; nt < 2; nt++)
        bfr[nt] = *(const bf16x8*)&Bls[(wc * 32 + nt * 16 + m15) * 64 + (ks * 4 + q) * 8];
#pragma unroll
      for (int mt = 0; mt < 4; mt++)
#pragma unroll
        for (int nt = 0; nt < 2; nt++)
          acc[mt][nt] = __builtin_amdgcn_mfma_f32_16x16x32_bf16(af[mt], bfr[nt],
                                                                acc[mt][nt], 0, 0, 0);
    }
  }
#pragma unroll
  for (int mt = 0; mt < 4; mt++) {
#pragma unroll
    for (int nt = 0; nt < 2; nt++) {
      int gc = bn * 64 + wc * 32 + nt * 16 + m15;
#pragma unroll
      for (int r = 0; r < 4; r++) {
        int gr = bm * 128 + wr * 64 + mt * 16 + q * 4 + r;
        size_t off = (size_t)gr * N + gc;
        float v = acc[mt][nt][r];
        if (EPI == 1) v = gelu_f(v);
        if (EPI == 2) v += R[off];
        if (OBF16) ((__bf16*)Cout)[off] = (__bf16)v;
        else       ((float*)Cout)[off] = v;
      }
    }
  }
}

// -------- split fp32 -> bf16 hi + bf16 lo (exact residual) --------
__global__ __launch_bounds__(256) void split_bf16_kernel(const float* __restrict__ src,
                                                         __bf16* __restrict__ hi,
                                                         __bf16* __restrict__ lo) {
  int i = blockIdx.x * 256 + threadIdx.x;
  float4 v = ((const float4*)src)[i];
  float xs[4] = {v.x, v.y, v.z, v.w};
  bf16x4 hv, lv;
#pragma unroll
  for (int e = 0; e < 4; e++) {
    __bf16 h = (__bf16)xs[e];
    hv[e] = h;
    lv[e] = (__bf16)(xs[e] - (float)h);
  }
  *(bf16x4*)&hi[(size_t)i * 4] = hv;
  *(bf16x4*)&lo[(size_t)i * 4] = lv;
}

// ---- per-head transpose + split: qkv v-part -> vt[b,h][64][512] bf16 ------
__global__ __launch_bounds__(256) void vtrans_split_kernel(const float* __restrict__ qkv,
                                                           __bf16* __restrict__ vth,
                                                           __bf16* __restrict__ vtl) {
  __shared__ float tile[64 * 68];
  int tt = blockIdx.x, h = blockIdx.y, b = blockIdx.z;
  int t = threadIdx.x;
#pragma unroll
  for (int i = 0; i < 4; i++) {
    int lin = i * 256 + t, row = lin >> 4, c = (lin & 15) * 4;
    float4 x = *(const float4*)(qkv + ((size_t)(b * NN) + tt * 64 + row) * QKVS + 1024 + h * DHH + c);
    *(float4*)&tile[row * 68 + c] = x;
  }
  __syncthreads();
  int d = t >> 2, tb = (t & 3) * 16;
  float xs[16];
#pragma unroll
  for (int j = 0; j < 16; j++) xs[j] = tile[(tb + j) * 68 + d];
  bf16x8 h0, h1, l0, l1;
#pragma unroll
  for (int j = 0; j < 8; j++) {
    __bf16 a = (__bf16)xs[j];
    h0[j] = a; l0[j] = (__bf16)(xs[j] - (float)a);
    __bf16 bmv = (__bf16)xs[8 + j];
    h1[j] = bmv; l1[j] = (__bf16)(xs[8 + j] - (float)bmv);
  }
  size_t ob = ((size_t)(b * HH + h) * 64 + d) * NN + tt * 64 + tb;
  *(bf16x8*)(vth + ob) = h0; *(bf16x8*)(vth + ob + 8) = h1;
  *(bf16x8*)(vtl + ob) = l0; *(bf16x8*)(vtl + ob + 8) = l1;
}

// ============ kNN path A: MFMA score GEMM -> S (chunk-local, fp32) =========
// 32 q-rows per block, grid (16, nbh) = 256 blocks (full machine). R8 measured
// the 64-row/128-block variant at HALF occupancy -> 2x slower. Keep 32.
__global__ __launch_bounds__(256) void knn_score_mfma(const float* __restrict__ q,
                                                      const __bf16* __restrict__ khi,
                                                      const __bf16* __restrict__ klo,
                                                      float* __restrict__ S,
                                                      int bh0) {
  __shared__ __bf16 Kls[2][128 * 72];        // hi / lo staging, stride 72
  int it = blockIdx.x, bh = bh0 + blockIdx.y;
  int b = bh >> 3, h = bh & 7;
  int t = threadIdx.x;
  int lane = t & 63, w = t >> 6;
  int m15 = lane & 15, kg = lane >> 4;
  const float scale = 0.125f;

  bf16x8 aqh[2][2], aql[2][2];
#pragma unroll
  for (int rf = 0; rf < 2; rf++)
#pragma unroll
    for (int ks = 0; ks < 2; ks++) {
      const float* qp = q + ((size_t)(b * NN) + it * 32 + rf * 16 + m15) * QKVS +
                        h * DHH + ks * 32 + kg * 8;
      float4 x0 = *(const float4*)qp;
      float4 x1 = *(const float4*)(qp + 4);
      float xs[8] = {x0.x, x0.y, x0.z, x0.w, x1.x, x1.y, x1.z, x1.w};
#pragma unroll
      for (int e = 0; e < 8; e++) {
        __bf16 hv = (__bf16)xs[e];
        aqh[rf][ks][e] = hv;
        aql[rf][ks][e] = (__bf16)(xs[e] - (float)hv);
      }
    }

  const __bf16* khb = khi + (size_t)b * MEMM * DHH;
  const __bf16* klb = klo + (size_t)b * MEMM * DHH;
  size_t srow0 = (size_t)blockIdx.y * NN + it * 32;  // chunk-local row base

  for (int mt = 0; mt < MEMM; mt += 128) {
    __syncthreads();
#pragma unroll
    for (int i = 0; i < 4; i++) {
      int lin = i * 256 + t;
      int row = lin >> 3, cb = (lin & 7) * 8;
      *(uint4*)&Kls[0][row * 72 + cb] = *(const uint4*)(khb + (size_t)(mt + row) * DHH + cb);
      *(uint4*)&Kls[1][row * 72 + cb] = *(const uint4*)(klb + (size_t)(mt + row) * DHH + cb);
    }
    __syncthreads();
    f32x4 acc[2][2] = {};
#pragma unroll
    for (int ks = 0; ks < 2; ks++) {
      bf16x8 bh2[2], bl2[2];
#pragma unroll
      for (int cf = 0; cf < 2; cf++) {
        int row = w * 32 + cf * 16 + m15;
        bh2[cf] = *(const bf16x8*)&Kls[0][row * 72 + ks * 32 + kg * 8];
        bl2[cf] = *(const bf16x8*)&Kls[1][row * 72 + ks * 32 + kg * 8];
      }
#pragma unroll
      for (int rf = 0; rf < 2; rf++)
#pragma unroll
        for (int cf = 0; cf < 2; cf++) {
          acc[rf][cf] = __builtin_amdgcn_mfma_f32_16x16x32_bf16(aqh[rf][ks], bh2[cf], acc[rf][cf], 0, 0, 0);
          acc[rf][cf] = __builtin_amdgcn_mfma_f32_16x16x32_bf16(aql[rf][ks], bh2[cf], acc[rf][cf], 0, 0, 0);
          acc[rf][cf] = __builtin_amdgcn_mfma_f32_16x16x32_bf16(aqh[rf][ks], bl2[cf], acc[rf][cf], 0, 0, 0);
        }
    }
#pragma unroll
    for (int rf = 0; rf < 2; rf++)
#pragma unroll
      for (int cf = 0; cf < 2; cf++) {
        int col = mt + w * 32 + cf * 16 + m15;
#pragma unroll
        for (int rr = 0; rr < 4; rr++)
          S[(srow0 + rf * 16 + kg * 4 + rr) * MEMM + col] = acc[rf][cf][rr] * scale;
      }
  }
}

// ============ kNN path B: exact top-32 per row via bit-serial radix =========
// Lane owns cands {i*256 + lane*4 + e}: 16 dwordx4 loads (1 KB/wave/instr).
// Count: 64 independent VALU adds + 6-step shuffle reduce (R6-measured form).
__global__ __launch_bounds__(256, 4) void knn_select_kernel(const float* __restrict__ S,
                                                            float* __restrict__ topv,
                                                            int* __restrict__ topi,
                                                            int row_base) {
  int lane = threadIdx.x & 63;
  int row = blockIdx.x * 4 + (threadIdx.x >> 6);
  const float* srow = S + (size_t)row * MEMM;
  unsigned u[64];
#pragma unroll
  for (int i = 0; i < 16; i++) {
    uint4 v = *(const uint4*)(srow + i * 256 + lane * 4);
    unsigned vs[4] = {v.x, v.y, v.z, v.w};
#pragma unroll
    for (int e = 0; e < 4; e++) {
      unsigned bb = vs[e];
      u[i * 4 + e] = (bb & 0x80000000u) ? ~bb : (bb | 0x80000000u);
    }
  }
  unsigned T = 0;
#pragma unroll 1
  for (int bit = 31; bit >= 0; --bit) {
    unsigned Tp = T | (1u << bit);
    int c = 0;
#pragma unroll
    for (int j = 0; j < 64; j++) c += (u[j] >= Tp) ? 1 : 0;
#pragma unroll
    for (int m = 32; m; m >>= 1) c += __shfl_xor(c, m, 64);
    if (c >= TOPKK) {
      T = Tp;
      if (c == TOPKK) break;
    }
  }
  unsigned long long below = (1ull << lane) - 1ull;
  float* tvrow = topv + (size_t)(row_base + row) * TOPKK;
  int* tirow = topi + (size_t)(row_base + row) * TOPKK;
  int g = 0;
#pragma unroll
  for (int i = 0; i < 16; i++)
#pragma unroll
    for (int e = 0; e < 4; e++) {
      int j = i * 4 + e;
      bool f = u[j] > T;
      unsigned long long m = __ballot(f);
      if (f) {
        int pos = g + __popcll(m & below);
        union { unsigned b; float f2; } rv;
        rv.b = (u[j] & 0x80000000u) ? (u[j] & 0x7fffffffu) : ~u[j];
        tvrow[pos] = rv.f2;
        tirow[pos] = i * 256 + lane * 4 + e;
      }
      g += __popcll(m);
    }
#pragma unroll 1
  for (int i = 0; i < 16 && g < TOPKK; i++)
#pragma unroll
    for (int e = 0; e < 4; e++) {
      int j = i * 4 + e;
      bool f = (u[j] == T);
      unsigned long long m = __ballot(f);
      if (f) {
        int pos = g + __popcll(m & below);
        if (pos < TOPKK) {
          union { unsigned b; float f2; } rv;
          rv.b = (T & 0x80000000u) ? (T & 0x7fffffffu) : ~T;
          tvrow[pos] = rv.f2;
          tirow[pos] = i * 256 + lane * 4 + e;
        }
      }
      g += __popcll(m);
    }
}

// ---------------- top-32 insert helper (fused fallback only) ----------------
__device__ __forceinline__ void insert32vi(float (&rtv)[32], int (&rti)[32],
                                           float sv, int idx, float& thr) {
  float mv = rtv[0], mv2 = INFINITY;
  int mi = 0;
#pragma unroll
  for (int k = 1; k < 32; k++) {
    float v = rtv[k];
    bool lt = v < mv;
    mv2 = lt ? mv : fminf(mv2, v);
    mv = lt ? v : mv;
    mi = lt ? k : mi;
  }
#pragma unroll
  for (int k = 0; k < 32; k++) {
    bool hit = (k == mi);
    rtv[k] = hit ? sv : rtv[k];
    rti[k] = hit ? idx : rti[k];
  }
  thr = fminf(mv2, sv);
}

// ============ fused MFMA score GEMM + top-32 (FALLBACK, tiny ws) ===========
__global__ __launch_bounds__(256) void knn_mfma_topk(const float* __restrict__ q,
                                                     const __bf16* __restrict__ khi,
                                                     const __bf16* __restrict__ klo,
                                                     float* __restrict__ topv,
                                                     int* __restrict__ topi) {
  __shared__ __bf16 Kls[2][128 * 72];
  __shared__ float scb[32][132];
  __shared__ unsigned short midx[32 * 260];
  __shared__ float rthr[8][32];
  int it = blockIdx.x, h = blockIdx.y, b = blockIdx.z;
  int t = threadIdx.x;
  int lane = t & 63, w = t >> 6;
  int m15 = lane & 15, kg = lane >> 4;
  const float scale = 0.125f;
  bf16x8 aqh[2][2], aql[2][2];
#pragma unroll
  for (int rf = 0; rf < 2; rf++)
#pragma unroll
    for (int ks = 0; ks < 2; ks++) {
      const float* qp = q + ((size_t)(b * NN) + it * 32 + rf * 16 + m15) * QKVS +
                        h * DHH + ks * 32 + kg * 8;
      float4 x0 = *(const float4*)qp;
      float4 x1 = *(const float4*)(qp + 4);
      float xs[8] = {x0.x, x0.y, x0.z, x0.w, x1.x, x1.y, x1.z, x1.w};
#pragma unroll
      for (int e = 0; e < 8; e++) {
        __bf16 hv = (__bf16)xs[e];
        aqh[rf][ks][e] = hv;
        aql[rf][ks][e] = (__bf16)(xs[e] - (float)hv);
      }
    }
  int r = t & 31, p = t >> 5;
  rthr[p][r] = -INFINITY;
  float rtv[32]; int rti[32];
#pragma unroll
  for (int k = 0; k < 32; k++) { rtv[k] = -INFINITY; rti[k] = 0; }
  float thr = -INFINITY;
  const __bf16* khb = khi + (size_t)b * MEMM * DHH;
  const __bf16* klb = klo + (size_t)b * MEMM * DHH;

  for (int mt = 0; mt < MEMM; mt += 128) {
    __syncthreads();
#pragma unroll
    for (int i = 0; i < 4; i++) {
      int lin = i * 256 + t;
      int row = lin >> 3, cb = (lin & 7) * 8;
      *(uint4*)&Kls[0][row * 72 + cb] = *(const uint4*)(khb + (size_t)(mt + row) * DHH + cb);
      *(uint4*)&Kls[1][row * 72 + cb] = *(const uint4*)(klb + (size_t)(mt + row) * DHH + cb);
    }
    __syncthreads();
    f32x4 acc[2][2] = {};
#pragma unroll
    for (int ks = 0; ks < 2; ks++) {
      bf16x8 bh2[2], bl2[2];
#pragma unroll
      for (int cf = 0; cf < 2; cf++) {
        int row = w * 32 + cf * 16 + m15;
        bh2[cf] = *(const bf16x8*)&Kls[0][row * 72 + ks * 32 + kg * 8];
        bl2[cf] = *(const bf16x8*)&Kls[1][row * 72 + ks * 32 + kg * 8];
      }
#pragma unroll
      for (int rf = 0; rf < 2; rf++)
#pragma unroll
        for (int cf = 0; cf < 2; cf++) {
          acc[rf][cf] = __builtin_amdgcn_mfma_f32_16x16x32_bf16(aqh[rf][ks], bh2[cf], acc[rf][cf], 0, 0, 0);
          acc[rf][cf] = __builtin_amdgcn_mfma_f32_16x16x32_bf16(aql[rf][ks], bh2[cf], acc[rf][cf], 0, 0, 0);
          acc[rf][cf] = __builtin_amdgcn_mfma_f32_16x16x32_bf16(aqh[rf][ks], bl2[cf], acc[rf][cf], 0, 0, 0);
        }
    }
#pragma unroll
    for (int rf = 0; rf < 2; rf++)
#pragma unroll
      for (int cf = 0; cf < 2; cf++) {
        int col = w * 32 + cf * 16 + m15;
#pragma unroll
        for (int rr = 0; rr < 4; rr++)
          scb[rf * 16 + kg * 4 + rr][col] = acc[rf][cf][rr] * scale;
      }
    __syncthreads();
    {
      float B2 = rthr[0][r];
#pragma unroll
      for (int j = 1; j < 8; j++) B2 = fmaxf(B2, rthr[j][r]);
      const float* srow = &scb[r][16 * p];
#pragma unroll 1
      for (int c = 0; c < 16; c++) {
        int cc = (c + r) & 15;
        float sv = srow[cc];
        if (sv > fmaxf(thr, B2))
          insert32vi(rtv, rti, sv, mt + 16 * p + cc, thr);
      }
      rthr[p][r] = thr;
    }
  }
  __syncthreads();
  float* mvals = (float*)&Kls[0][0];
#pragma unroll
  for (int k = 0; k < 32; k++) {
    int cc = (k + r) & 31;
    mvals[(size_t)260 * r + 32 * p + cc] = rtv[k];
    midx[(size_t)260 * r + 32 * p + cc] = (unsigned short)rti[k];
  }
  __syncthreads();
  if (t < 32) {
#pragma unroll 1
    for (int c = 0; c < 224; c++) {
      int cc = c + r; if (cc >= 224) cc -= 224;
      float sv = mvals[(size_t)260 * r + 32 + cc];
      if (sv > thr)
        insert32vi(rtv, rti, sv, (int)midx[(size_t)260 * r + 32 + cc], thr);
    }
    size_t rowg = ((size_t)b * HH + h) * NN + it * 32 + r;
#pragma unroll
    for (int k = 0; k < 32; k++) {
      topv[rowg * TOPKK + k] = rtv[k];
      topi[rowg * TOPKK + k] = rti[k];
    }
  }
}

// ======== MFMA flash attention (compensated bf16, swapped QK^T layout) =====
// 1-D grid 512: flat = bi*64 + (b*8+h) -> blocks of one (b,h) co-locate on
// one XCD (L2 reuse of K/V). K/V tile jt+1 prefetched to regs (T14).
__global__ __launch_bounds__(256) void attn_mfma_kernel(
    const float* __restrict__ qkv,
    const __bf16* __restrict__ vth, const __bf16* __restrict__ vtl,
    __bf16* __restrict__ ao, const float* __restrict__ topv,
    const int* __restrict__ topi, const float* __restrict__ mem_v, int knn) {
  __shared__ __align__(16) __bf16 smem[27648];   // 55296 B
  __bf16* Kh = smem;                 // [64][72]
  __bf16* Kl = smem + 4608;
  __bf16* Vh = smem + 9216;          // V^T [d 64][72]
  __bf16* Vl = smem + 13824;
  __bf16* Pw = smem + 18432;         // [wave][hi/lo][16][72]

  int flat = blockIdx.x;
  int bi = flat >> 6;
  int hb = flat & 63;
  int h = hb & 7, b = hb >> 3;
  int t = threadIdx.x, lane = t & 63, w = t >> 6;
  int q15 = lane & 15, g = lane >> 4;
  const float scale = 0.125f;

  bf16x8 qh[2], ql[2];
  {
    const float* qp = qkv + ((size_t)(b * NN) + bi * 64 + w * 16 + q15) * QKVS + h * DHH;
#pragma unroll
    for (int ks = 0; ks < 2; ks++) {
      float4 x0 = *(const float4*)(qp + ks * 32 + g * 8);
      float4 x1 = *(const float4*)(qp + ks * 32 + g * 8 + 4);
      float xs[8] = {x0.x, x0.y, x0.z, x0.w, x1.x, x1.y, x1.z, x1.w};
#pragma unroll
      for (int e = 0; e < 8; e++) {
        __bf16 hv = (__bf16)xs[e];
        qh[ks][e] = hv;
        ql[ks][e] = (__bf16)(xs[e] - (float)hv);
      }
    }
  }
  int tr = t >> 4, kc = (t & 15) * 4;      // K: rows tr, tr+16, tr+32, tr+48
  int td = t >> 3, tb = (t & 7) * 8;       // V: rows td, td+32
  float4 kp0, kp1, kp2, kp3;
  uint4 vhp0, vhp1, vlp0, vlp1;

#define LOAD_TILE(jt_) do {                                                        \
    const float* kb_ = qkv + ((size_t)(b * NN) + (jt_) * 64 + tr) * QKVS + 512 +   \
                       h * DHH + kc;                                               \
    kp0 = *(const float4*)kb_;                                                     \
    kp1 = *(const float4*)(kb_ + (size_t)16 * QKVS);                               \
    kp2 = *(const float4*)(kb_ + (size_t)32 * QKVS);                               \
    kp3 = *(const float4*)(kb_ + (size_t)48 * QKVS);                               \
    size_t vb_ = ((size_t)(b * HH + h) * 64 + td) * NN + (jt_) * 64 + tb;          \
    vhp0 = *(const uint4*)(vth + vb_);                                             \
    vhp1 = *(const uint4*)(vth + vb_ + (size_t)32 * NN);                           \
    vlp0 = *(const uint4*)(vtl + vb_);                                             \
    vlp1 = *(const uint4*)(vtl + vb_ + (size_t)32 * NN);                           \
  } while (0)

#define STORE_K(kp_, ro_) do {                                                     \
    bf16x4 hv_, lv_;                                                               \
    float e0_ = kp_.x, e1_ = kp_.y, e2_ = kp_.z, e3_ = kp_.w;                      \
    hv_[0] = (__bf16)e0_; lv_[0] = (__bf16)(e0_ - (float)hv_[0]);                  \
    hv_[1] = (__bf16)e1_; lv_[1] = (__bf16)(e1_ - (float)hv_[1]);                  \
    hv_[2] = (__bf16)e2_; lv_[2] = (__bf16)(e2_ - (float)hv_[2]);                  \
    hv_[3] = (__bf16)e3_; lv_[3] = (__bf16)(e3_ - (float)hv_[3]);                  \
    *(bf16x4*)&Kh[((ro_) + tr) * 72 + kc] = hv_;                                   \
    *(bf16x4*)&Kl[((ro_) + tr) * 72 + kc] = lv_;                                   \
  } while (0)

  float m_run = -INFINITY, l_run = 0.f;
  f32x4 opv[4] = {};
  int ntiles = bi + 1;
  LOAD_TILE(0);
  for (int jt = 0; jt < ntiles; jt++) {
    __syncthreads();
    STORE_K(kp0, 0); STORE_K(kp1, 16); STORE_K(kp2, 32); STORE_K(kp3, 48);
    *(uint4*)&Vh[td * 72 + tb] = vhp0;
    *(uint4*)&Vh[(32 + td) * 72 + tb] = vhp1;
    *(uint4*)&Vl[td * 72 + tb] = vlp0;
    *(uint4*)&Vl[(32 + td) * 72 + tb] = vlp1;
    if (jt + 1 < ntiles) LOAD_TILE(jt + 1);
    __syncthreads();
    int smax = (jt == bi) ? w : 3;
    float sc16[16];
    float tmax = -INFINITY;
#pragma unroll
    for (int s = 0; s < 4; s++) {
      if (s <= smax) {
        f32x4 accs = {};
#pragma unroll
        for (int ks = 0; ks < 2; ks++) {
          bf16x8 ah = *(const bf16x8*)&Kh[(s * 16 + q15) * 72 + ks * 32 + g * 8];
          bf16x8 al = *(const bf16x8*)&Kl[(s * 16 + q15) * 72 + ks * 32 + g * 8];
          accs = __builtin_amdgcn_mfma_f32_16x16x32_bf16(ah, qh[ks], accs, 0, 0, 0);
          accs = __builtin_amdgcn_mfma_f32_16x16x32_bf16(al, qh[ks], accs, 0, 0, 0);
          accs = __builtin_amdgcn_mfma_f32_16x16x32_bf16(ah, ql[ks], accs, 0, 0, 0);
        }
#pragma unroll
        for (int r = 0; r < 4; r++) {
          float sv = accs[r] * scale;
          if (jt == bi) {
            int kvg = jt * 64 + s * 16 + g * 4 + r;
            int qg = bi * 64 + w * 16 + q15;
            if (kvg > qg) sv = -INFINITY;
          }
          sc16[s * 4 + r] = sv;
          tmax = fmaxf(tmax, sv);
        }
      } else {
#pragma unroll
        for (int r = 0; r < 4; r++) sc16[s * 4 + r] = -INFINITY;
      }
    }
    tmax = fmaxf(tmax, __shfl_xor(tmax, 16, 64));
    tmax = fmaxf(tmax, __shfl_xor(tmax, 32, 64));
    float m_new = fmaxf(m_run, tmax);
    float psum = 0.f;
    __bf16 ph[16], pl[16];
#pragma unroll
    for (int i = 0; i < 16; i++) {
      float p = __expf(sc16[i] - m_new);
      psum += p;
      __bf16 hp = (__bf16)p;
      ph[i] = hp; pl[i] = (__bf16)(p - (float)hp);
    }
    psum += __shfl_xor(psum, 16, 64);
    psum += __shfl_xor(psum, 32, 64);
    float alpha = __expf(m_run - m_new);
    l_run = l_run * alpha + psum;
    m_run = m_new;
    __bf16* Ph = Pw + (w * 2 + 0) * 1152;
    __bf16* Pl = Pw + (w * 2 + 1) * 1152;
#pragma unroll
    for (int s = 0; s < 4; s++) {
      bf16x4 hv, lv;
#pragma unroll
      for (int r = 0; r < 4; r++) { hv[r] = ph[s * 4 + r]; lv[r] = pl[s * 4 + r]; }
      *(bf16x4*)&Ph[q15 * 72 + s * 16 + g * 4] = hv;
      *(bf16x4*)&Pl[q15 * 72 + s * 16 + g * 4] = lv;
    }
    __builtin_amdgcn_wave_barrier();
    float a0 = __shfl(alpha, g * 4 + 0, 64);
    float a1 = __shfl(alpha, g * 4 + 1, 64);
    float a2 = __shfl(alpha, g * 4 + 2, 64);
    float a3 = __shfl(alpha, g * 4 + 3, 64);
#pragma unroll
    for (int dsub = 0; dsub < 4; dsub++) {
      opv[dsub][0] *= a0; opv[dsub][1] *= a1;
      opv[dsub][2] *= a2; opv[dsub][3] *= a3;
    }
#pragma unroll
    for (int ks2 = 0; ks2 < 2; ks2++) {
      bf16x8 pah = *(const bf16x8*)&Ph[q15 * 72 + ks2 * 32 + g * 8];
      bf16x8 pal = *(const bf16x8*)&Pl[q15 * 72 + ks2 * 32 + g * 8];
#pragma unroll
      for (int dsub = 0; dsub < 4; dsub++) {
        bf16x8 vbh = *(const bf16x8*)&Vh[(dsub * 16 + q15) * 72 + ks2 * 32 + g * 8];
        bf16x8 vbl = *(const bf16x8*)&Vl[(dsub * 16 + q15) * 72 + ks2 * 32 + g * 8];
        opv[dsub] = __builtin_amdgcn_mfma_f32_16x16x32_bf16(pah, vbh, opv[dsub], 0, 0, 0);
        opv[dsub] = __builtin_amdgcn_mfma_f32_16x16x32_bf16(pal, vbh, opv[dsub], 0, 0, 0);
        opv[dsub] = __builtin_amdgcn_mfma_f32_16x16x32_bf16(pah, vbl, opv[dsub], 0, 0, 0);
      }
    }
  }
#undef LOAD_TILE
#undef STORE_K
  __syncthreads();
  float* scf  = (float*)smem;                 // [64][68] fp32
  float* marr = (float*)(smem + 8704);
  float* larr = marr + 64;
  float* aarr = marr + 128;
  float* sc2  = (float*)(smem + 9216);        // [64][33] fp32
  int*   pidx = (int*)(smem + 13824);         // [64][32] int
#pragma unroll
  for (int dsub = 0; dsub < 4; dsub++)
#pragma unroll
    for (int r = 0; r < 4; r++)
      scf[(w * 16 + g * 4 + r) * 68 + dsub * 16 + q15] = opv[dsub][r];
  if (g == 0) { marr[w * 16 + q15] = m_run; larr[w * 16 + q15] = l_run; }
  __syncthreads();
  int r_ = t & 63, w4 = t >> 6;
  float acc16[16];
  if (knn) {
    size_t rowbase = ((size_t)b * HH + h) * NN + bi * 64;
    for (int rr = w * 16; rr < w * 16 + 16; rr++) {
      float s = (lane < TOPKK) ? topv[(rowbase + rr) * TOPKK + lane] : -INFINITY;
      float m_old = marr[rr];
      float tm = s;
#pragma unroll
      for (int m = 32; m; m >>= 1) tm = fmaxf(tm, __shfl_xor(tm, m, 64));
      float m_new = fmaxf(m_old, tm);
      float p = __expf(s - m_new);
      float ts = p;
#pragma unroll
      for (int m = 32; m; m >>= 1) ts += __shfl_xor(ts, m, 64);
      float alpha = __expf(m_old - m_new);
      if (lane < TOPKK) {
        sc2[rr * 33 + lane] = p;
        pidx[rr * 32 + lane] = topi[(rowbase + rr) * TOPKK + lane];
      }
      if (lane == 0) {
        marr[rr] = m_new; larr[rr] = larr[rr] * alpha + ts; aarr[rr] = alpha;
      }
    }
    __syncthreads();
    float al = aarr[r_];
#pragma unroll
    for (int dd = 0; dd < 16; dd++) acc16[dd] = scf[r_ * 68 + w4 * 16 + dd] * al;
    const float* mvb = mem_v + (size_t)b * MEMM * DHH;
#pragma unroll 1
    for (int kk = 0; kk < TOPKK; kk++) {
      float p = sc2[r_ * 33 + kk];
      const float* mrow = mvb + (size_t)pidx[r_ * 32 + kk] * DHH + w4 * 16;
#pragma unroll
      for (int dd = 0; dd < 16; dd += 4) {
        float4 m4 = *(const float4*)(mrow + dd);
        acc16[dd] += p * m4.x; acc16[dd + 1] += p * m4.y;
        acc16[dd + 2] += p * m4.z; acc16[dd + 3] += p * m4.w;
      }
    }
  } else {
#pragma unroll
    for (int dd = 0; dd < 16; dd++) acc16[dd] = scf[r_ * 68 + w4 * 16 + dd];
  }
  float linv = 1.f / larr[r_];
  bf16x8 o0, o1;
#pragma unroll
  for (int j = 0; j < 8; j++) {
    o0[j] = (__bf16)(acc16[j] * linv);
    o1[j] = (__bf16)(acc16[8 + j] * linv);
  }
  __bf16* aop = ao + ((size_t)(b * NN) + bi * 64 + r_) * DD + h * DHH + w4 * 16;
  *(bf16x8*)aop = o0;
  *(bf16x8*)(aop + 8) = o1;
}

// ---------------- host ----------------
extern "C" void kernel_launch(void* const* d_in, const int* in_sizes, int n_in,
                              void* d_out, int out_size, void* d_ws, size_t ws_size,
                              hipStream_t stream) {
  const float* x_in  = (const float*)d_in[0];
  const float* Wq    = (const float*)d_in[1];
  const float* Wk    = (const float*)d_in[2];
  const float* Wv    = (const float*)d_in[3];
  const float* Wo    = (const float*)d_in[4];
  const float* ln1_s = (const float*)d_in[5];
  const float* ln1_b = (const float*)d_in[6];
  const float* ln2_s = (const float*)d_in[7];
  const float* ln2_b = (const float*)d_in[8];
  const float* W1    = (const float*)d_in[9];
  const float* W2    = (const float*)d_in[10];
  const float* lnf_s = (const float*)d_in[11];
  const float* lnf_b = (const float*)d_in[12];
  const float* mem_k = (const float*)d_in[13];
  const float* mem_v = (const float*)d_in[14];

  float* ws  = (float*)d_ws;
  float*  xb    = ws;
  float*  qkvb  = ws + 2097152;           // [4096][1536] fp32
  __bf16* hb16  = (__bf16*)(ws + 8388608);
  __bf16* ao16  = (__bf16*)(ws + 9437184);
  __bf16* wqT   = (__bf16*)(ws + 10485760);   // wq/wk/wv contiguous [1536][512]
  __bf16* woT   = (__bf16*)(ws + 10878976);
  __bf16* w1T   = (__bf16*)(ws + 11010048);
  __bf16* w2T   = (__bf16*)(ws + 11534336);
  float*  tvb   = ws + 12058624;
  int*    tib   = (int*)(ws + 13107200);
  __bf16* ffb16 = (__bf16*)(ws + 2097152);    // aliases qkvb (dead post-attn)
  __bf16* wkT   = wqT + 262144;
  __bf16* wvT   = wqT + 524288;
  __bf16* khi16 = (__bf16*)(ws + 8388608);
  __bf16* klo16 = (__bf16*)(ws + 9437184);

  // S chunk region after base layout; V^T hi/lo overlap it (lifetime-disjoint).
  const size_t base_floats = 14155776;
  const size_t slice_floats = (size_t)NN * MEMM;
  const size_t ws_floats = ws_size / sizeof(float);
  int nbh = 0;
  for (int c = 64; c >= 1; c >>= 1) {
    if (base_floats + (size_t)c * slice_floats <= ws_floats) { nbh = c; break; }
  }
  float* Sb = ws + base_floats;
  __bf16* vth = (__bf16*)(ws + base_floats);
  __bf16* vtl = (__bf16*)(ws + base_floats + 1048576);

  dim3 blk(256);
  const size_t DD2 = (size_t)DD * DD;
  for (int l = 0; l < DEPTHH; l++) {
    const float* xcur = (l == 0) ? x_in : xb;
    transpose_all_kernel<<<dim3(3072), blk, 0, stream>>>(
        Wq + l * DD2, Wk + l * DD2, Wv + l * DD2, Wo + l * DD2,
        W1 + (size_t)l * DD * FFF, W2 + (size_t)l * FFF * DD,
        wqT, wkT, wvT, woT, w1T, w2T);

    ln_kernel<1><<<NT, blk, 0, stream>>>(xcur, ln1_s + l * DD, ln1_b + l * DD, hb16);
    gemm_mfma64<0, 0><<<dim3(24, 32), blk, 0, stream>>>(hb16, wqT, nullptr, qkvb, NT, QKVS, DD);
    int mi = (l == 3) ? 0 : ((l == 4) ? 1 : -1);
    if (mi >= 0) {
      const float* mk = mem_k + (size_t)mi * BB * MEMM * DHH;
      split_bf16_kernel<<<dim3(BB * MEMM * DHH / 1024), blk, 0, stream>>>(mk, khi16, klo16);
      if (nbh > 0) {
        for (int bh0 = 0; bh0 < BB * HH; bh0 += nbh) {
          knn_score_mfma<<<dim3(16, nbh), blk, 0, stream>>>(qkvb, khi16, klo16, Sb, bh0);
          knn_select_kernel<<<dim3(nbh * NN / 4), blk, 0, stream>>>(Sb, tvb, tib, bh0 * NN);
        }
      } else {
        knn_mfma_topk<<<dim3(16, 8, 8), blk, 0, stream>>>(qkvb, khi16, klo16, tvb, tib);
      }
    }
    vtrans_split_kernel<<<dim3(8, 8, 8), blk, 0, stream>>>(qkvb, vth, vtl);
    attn_mfma_kernel<<<dim3(512), blk, 0, stream>>>(
        qkvb, vth, vtl, ao16, tvb, tib,
        mem_v + (size_t)(mi < 0 ? 0 : mi) * BB * MEMM * DHH, mi >= 0 ? 1 : 0);
    gemm_mfma64<2, 0><<<dim3(8, 32), blk, 0, stream>>>(ao16, woT, xcur, xb, NT, DD, DD);
    ln_kernel<1><<<NT, blk, 0, stream>>>(xb, ln2_s + l * DD, ln2_b + l * DD, hb16);
    gemm_mfma128<1, 1><<<dim3(16, 32), blk, 0, stream>>>(hb16, w1T, nullptr, ffb16, NT, FFF, DD);
    gemm_mfma64<2, 0><<<dim3(8, 32), blk, 0, stream>>>(ffb16, w2T, xb, xb, NT, DD, FFF);
  }
  ln_kernel<0><<<NT, blk, 0, stream>>>(xb, lnf_s, lnf_b, (float*)d_out);
}

// Round 10
// 1931.844 us; speedup vs baseline: 1.1031x; 1.0223x over previous
//
#include <hip/hip_runtime.h>
#include <math.h>

#define BB 8
#define NN 512
#define DD 512
#define HH 8
#define DHH 64
#define FFF 2048
#define MEMM 4096
#define TOPKK 32
#define DEPTHH 6
#define NT (BB*NN)   /* 4096 tokens */
#define QKVS 1536    /* fused qkv row stride */

typedef __bf16 bf16x8 __attribute__((ext_vector_type(8)));
typedef __bf16 bf16x4 __attribute__((ext_vector_type(4)));
typedef float f32x4 __attribute__((ext_vector_type(4)));

// ---------------- LayerNorm (fp32 in, fp32 or bf16 out) ----------------
template <int OBF16>
__global__ __launch_bounds__(256) void ln_kernel(const float* __restrict__ xin,
                                                 const float* __restrict__ g,
                                                 const float* __restrict__ bt,
                                                 void* __restrict__ outv) {
  __shared__ float red[4];
  int tok = blockIdx.x;
  const float* xr = xin + (size_t)tok * DD;
  int t = threadIdx.x;
  float v0 = xr[t], v1 = xr[t + 256];
  float s = v0 + v1;
#pragma unroll
  for (int m = 32; m; m >>= 1) s += __shfl_xor(s, m, 64);
  if ((t & 63) == 0) red[t >> 6] = s;
  __syncthreads();
  float mean = (red[0] + red[1] + red[2] + red[3]) * (1.0f / 512.0f);
  float d0 = v0 - mean, d1 = v1 - mean;
  float vv = d0 * d0 + d1 * d1;
#pragma unroll
  for (int m = 32; m; m >>= 1) vv += __shfl_xor(vv, m, 64);
  __syncthreads();
  if ((t & 63) == 0) red[t >> 6] = vv;
  __syncthreads();
  float var = (red[0] + red[1] + red[2] + red[3]) * (1.0f / 512.0f);
  float inv = rsqrtf(var + 1e-5f);
  float o0 = d0 * inv * g[t] + bt[t];
  float o1 = d1 * inv * g[t + 256] + bt[t + 256];
  if (OBF16) {
    __bf16* out = (__bf16*)outv;
    out[(size_t)tok * DD + t] = (__bf16)o0;
    out[(size_t)tok * DD + t + 256] = (__bf16)o1;
  } else {
    float* out = (float*)outv;
    out[(size_t)tok * DD + t] = o0;
    out[(size_t)tok * DD + t + 256] = o1;
  }
}

__device__ inline float gelu_f(float x) {
  float x3 = x * x * x;
  return 0.5f * x * (1.0f + tanhf(0.7978845608028654f * (x + 0.044715f * x3)));
}

// --------- batched weight transpose+convert: all 6 weights, one launch ------
__global__ __launch_bounds__(256) void transpose_all_kernel(
    const float* __restrict__ Wq, const float* __restrict__ Wk,
    const float* __restrict__ Wv, const float* __restrict__ Wo,
    const float* __restrict__ W1, const float* __restrict__ W2,
    __bf16* __restrict__ wqT, __bf16* __restrict__ wkT,
    __bf16* __restrict__ wvT, __bf16* __restrict__ woT,
    __bf16* __restrict__ w1T, __bf16* __restrict__ w2T) {
  __shared__ float tile[32][33];
  int tid = blockIdx.x;
  const float* src; __bf16* dst; int K, N, tt;
  if (tid < 1024) {
    int which = tid >> 8; tt = tid & 255; K = 512; N = 512;
    src = (which == 0) ? Wq : (which == 1) ? Wk : (which == 2) ? Wv : Wo;
    dst = (which == 0) ? wqT : (which == 1) ? wkT : (which == 2) ? wvT : woT;
  } else if (tid < 2048) {
    tt = tid - 1024; K = 512; N = 2048; src = W1; dst = w1T;
  } else {
    tt = tid - 2048; K = 2048; N = 512; src = W2; dst = w2T;
  }
  int nx = N >> 5;
  int n0 = (tt % nx) * 32, k0 = (tt / nx) * 32;
  int tx = threadIdx.x & 31, ty = threadIdx.x >> 5;
#pragma unroll
  for (int i = 0; i < 4; i++) {
    int r = ty + i * 8;
    tile[r][tx] = src[(size_t)(k0 + r) * N + n0 + tx];
  }
  __syncthreads();
#pragma unroll
  for (int i = 0; i < 4; i++) {
    int r = ty + i * 8;
    dst[(size_t)(n0 + r) * K + k0 + tx] = (__bf16)tile[tx][r];
  }
}

// -------- async global->LDS 16B helper (wave-uniform lds base + lane*16) ----
__device__ __forceinline__ void gload16(const __bf16* g, __bf16* lds) {
  __builtin_amdgcn_global_load_lds(
      (const __attribute__((address_space(1))) void*)g,
      (__attribute__((address_space(3))) void*)lds, 16, 0, 0);
}

// ------- bf16 MFMA GEMM, 128x128 tile (for wide-N: FF1) --------------------
template <int EPI, int OBF16>
__global__ __launch_bounds__(256) void gemm_mfma128(const __bf16* __restrict__ A,
                                                    const __bf16* __restrict__ Bt,
                                                    const float* __restrict__ R,
                                                    void* __restrict__ Cout,
                                                    int M, int N, int K) {
  __shared__ __align__(16) __bf16 Als[128 * 64];
  __shared__ __align__(16) __bf16 Bls[128 * 64];
  int t = threadIdx.x;
  int bn = blockIdx.x, bm = blockIdx.y;
  int lane = t & 63, w = t >> 6;
  int wr = w >> 1, wc = w & 1;
  int m15 = lane & 15, q = lane >> 4;
  f32x4 acc[4][4] = {};
  for (int kt = 0; kt < K; kt += 64) {
    __syncthreads();
#pragma unroll
    for (int i = 0; i < 4; i++) {
      int rg = w * 32 + i * 8;
      int row = rg + (lane >> 3);
      int lcol = (lane & 7) * 8;
      gload16(A + (size_t)(bm * 128 + row) * K + kt + lcol, &Als[rg * 64]);
      gload16(Bt + (size_t)(bn * 128 + row) * K + kt + lcol, &Bls[rg * 64]);
    }
    __syncthreads();
#pragma unroll
    for (int ks = 0; ks < 2; ks++) {
      bf16x8 af[4], bfr[4];
#pragma unroll
      for (int mt = 0; mt < 4; mt++)
        af[mt] = *(const bf16x8*)&Als[(wr * 64 + mt * 16 + m15) * 64 + (ks * 4 + q) * 8];
#pragma unroll
      for (int nt = 0; nt < 4; nt++)
        bfr[nt] = *(const bf16x8*)&Bls[(wc * 64 + nt * 16 + m15) * 64 + (ks * 4 + q) * 8];
#pragma unroll
      for (int mt = 0; mt < 4; mt++)
#pragma unroll
        for (int nt = 0; nt < 4; nt++)
          acc[mt][nt] = __builtin_amdgcn_mfma_f32_16x16x32_bf16(af[mt], bfr[nt],
                                                                acc[mt][nt], 0, 0, 0);
    }
  }
#pragma unroll
  for (int mt = 0; mt < 4; mt++) {
#pragma unroll
    for (int nt = 0; nt < 4; nt++) {
      int gc = bn * 128 + wc * 64 + nt * 16 + m15;
#pragma unroll
      for (int r = 0; r < 4; r++) {
        int gr = bm * 128 + wr * 64 + mt * 16 + q * 4 + r;
        size_t off = (size_t)gr * N + gc;
        float v = acc[mt][nt][r];
        if (EPI == 1) v = gelu_f(v);
        if (EPI == 2) v += R[off];
        if (OBF16) ((__bf16*)Cout)[off] = (__bf16)v;
        else       ((float*)Cout)[off] = v;
      }
    }
  }
}

// ------- bf16 MFMA GEMM, 128x64 tile (for narrow-N: QKV/Wo/FF2 grid fill) --
template <int EPI, int OBF16>
__global__ __launch_bounds__(256) void gemm_mfma64(const __bf16* __restrict__ A,
                                                   const __bf16* __restrict__ Bt,
                                                   const float* __restrict__ R,
                                                   void* __restrict__ Cout,
                                                   int M, int N, int K) {
  __shared__ __align__(16) __bf16 Als[128 * 64];
  __shared__ __align__(16) __bf16 Bls[64 * 64];
  int t = threadIdx.x;
  int bn = blockIdx.x, bm = blockIdx.y;
  int lane = t & 63, w = t >> 6;
  int wr = w >> 1, wc = w & 1;
  int m15 = lane & 15, q = lane >> 4;
  f32x4 acc[4][2] = {};
  for (int kt = 0; kt < K; kt += 64) {
    __syncthreads();
#pragma unroll
    for (int i = 0; i < 4; i++) {
      int rg = w * 32 + i * 8;
      int row = rg + (lane >> 3);
      int lcol = (lane & 7) * 8;
      gload16(A + (size_t)(bm * 128 + row) * K + kt + lcol, &Als[rg * 64]);
    }
#pragma unroll
    for (int i = 0; i < 2; i++) {
      int rg = w * 16 + i * 8;
      int row = rg + (lane >> 3);
      int lcol = (lane & 7) * 8;
      gload16(Bt + (size_t)(bn * 64 + row) * K + kt + lcol, &Bls[rg * 64]);
    }
    __syncthreads();
#pragma unroll
    for (int ks = 0; ks < 2; ks++) {
      bf16x8 af[4], bfr[2];
#pragma unroll
      for (int mt = 0; mt < 4; mt++)
        af[mt] = *(const bf16x8*)&Als[(wr * 64 + mt * 16 + m15) * 64 + (ks * 4 + q) * 8];
#pragma unroll
      for (int nt = 0; nt < 2; nt++)
        bfr[nt] = *(const bf16x8*)&Bls[(wc * 32 + nt * 16 + m15) * 64 + (ks * 4 + q) * 8];
#pragma unroll
      for (int mt = 0; mt < 4; mt++)
#pragma unroll
        for (int nt = 0; nt < 2; nt++)
          acc[mt][nt] = __builtin_amdgcn_mfma_f32_16x16x32_bf16(af[mt], bfr[nt],
                                                                acc[mt][nt], 0, 0, 0);
    }
  }
#pragma unroll
  for (int mt = 0; mt < 4; mt++) {
#pragma unroll
    for (int nt = 0; nt < 2; nt++) {
      int gc = bn * 64 + wc * 32 + nt * 16 + m15;
#pragma unroll
      for (int r = 0; r < 4; r++) {
        int gr = bm * 128 + wr * 64 + mt * 16 + q * 4 + r;
        size_t off = (size_t)gr * N + gc;
        float v = acc[mt][nt][r];
        if (EPI == 1) v = gelu_f(v);
        if (EPI == 2) v += R[off];
        if (OBF16) ((__bf16*)Cout)[off] = (__bf16)v;
        else       ((float*)Cout)[off] = v;
      }
    }
  }
}

// -------- split fp32 -> bf16 hi + bf16 lo (exact residual) --------
__global__ __launch_bounds__(256) void split_bf16_kernel(const float* __restrict__ src,
                                                         __bf16* __restrict__ hi,
                                                         __bf16* __restrict__ lo) {
  int i = blockIdx.x * 256 + threadIdx.x;
  float4 v = ((const float4*)src)[i];
  float xs[4] = {v.x, v.y, v.z, v.w};
  bf16x4 hv, lv;
#pragma unroll
  for (int e = 0; e < 4; e++) {
    __bf16 h = (__bf16)xs[e];
    hv[e] = h;
    lv[e] = (__bf16)(xs[e] - (float)h);
  }
  *(bf16x4*)&hi[(size_t)i * 4] = hv;
  *(bf16x4*)&lo[(size_t)i * 4] = lv;
}

// ---- per-head transpose + split: qkv v-part -> vt[b,h][64][512] bf16 ------
__global__ __launch_bounds__(256) void vtrans_split_kernel(const float* __restrict__ qkv,
                                                           __bf16* __restrict__ vth,
                                                           __bf16* __restrict__ vtl) {
  __shared__ float tile[64 * 68];
  int tt = blockIdx.x, h = blockIdx.y, b = blockIdx.z;
  int t = threadIdx.x;
#pragma unroll
  for (int i = 0; i < 4; i++) {
    int lin = i * 256 + t, row = lin >> 4, c = (lin & 15) * 4;
    float4 x = *(const float4*)(qkv + ((size_t)(b * NN) + tt * 64 + row) * QKVS + 1024 + h * DHH + c);
    *(float4*)&tile[row * 68 + c] = x;
  }
  __syncthreads();
  int d = t >> 2, tb = (t & 3) * 16;
  float xs[16];
#pragma unroll
  for (int j = 0; j < 16; j++) xs[j] = tile[(tb + j) * 68 + d];
  bf16x8 h0, h1, l0, l1;
#pragma unroll
  for (int j = 0; j < 8; j++) {
    __bf16 a = (__bf16)xs[j];
    h0[j] = a; l0[j] = (__bf16)(xs[j] - (float)a);
    __bf16 bmv = (__bf16)xs[8 + j];
    h1[j] = bmv; l1[j] = (__bf16)(xs[8 + j] - (float)bmv);
  }
  size_t ob = ((size_t)(b * HH + h) * 64 + d) * NN + tt * 64 + tb;
  *(bf16x8*)(vth + ob) = h0; *(bf16x8*)(vth + ob + 8) = h1;
  *(bf16x8*)(vtl + ob) = l0; *(bf16x8*)(vtl + ob + 8) = l1;
}

// ============ kNN path A: MFMA score GEMM -> S (chunk-local, fp32) =========
// 32 q-rows per block; grid (16, nbh, MSPLIT): z partitions the mem-candidate
// range (pure loop split, identical outputs). R9 measured grid (16,16)=256
// blocks at 1.7 TB/s write / 10.7% occupancy -> store-latency-bound; 4x the
// blocks gives 4 blocks/CU of in-flight stores.
#define MSPLIT 4
__global__ __launch_bounds__(256) void knn_score_mfma(const float* __restrict__ q,
                                                      const __bf16* __restrict__ khi,
                                                      const __bf16* __restrict__ klo,
                                                      float* __restrict__ S,
                                                      int bh0) {
  __shared__ __bf16 Kls[2][128 * 72];        // hi / lo staging, stride 72
  int it = blockIdx.x, bh = bh0 + blockIdx.y;
  int mz = blockIdx.z;
  int b = bh >> 3, h = bh & 7;
  int t = threadIdx.x;
  int lane = t & 63, w = t >> 6;
  int m15 = lane & 15, kg = lane >> 4;
  const float scale = 0.125f;

  bf16x8 aqh[2][2], aql[2][2];
#pragma unroll
  for (int rf = 0; rf < 2; rf++)
#pragma unroll
    for (int ks = 0; ks < 2; ks++) {
      const float* qp = q + ((size_t)(b * NN) + it * 32 + rf * 16 + m15) * QKVS +
                        h * DHH + ks * 32 + kg * 8;
      float4 x0 = *(const float4*)qp;
      float4 x1 = *(const float4*)(qp + 4);
      float xs[8] = {x0.x, x0.y, x0.z, x0.w, x1.x, x1.y, x1.z, x1.w};
#pragma unroll
      for (int e = 0; e < 8; e++) {
        __bf16 hv = (__bf16)xs[e];
        aqh[rf][ks][e] = hv;
        aql[rf][ks][e] = (__bf16)(xs[e] - (float)hv);
      }
    }

  const __bf16* khb = khi + (size_t)b * MEMM * DHH;
  const __bf16* klb = klo + (size_t)b * MEMM * DHH;
  size_t srow0 = (size_t)blockIdx.y * NN + it * 32;  // chunk-local row base

  const int mlo = mz * (MEMM / MSPLIT), mhi = mlo + MEMM / MSPLIT;
  for (int mt = mlo; mt < mhi; mt += 128) {
    __syncthreads();
#pragma unroll
    for (int i = 0; i < 4; i++) {
      int lin = i * 256 + t;
      int row = lin >> 3, cb = (lin & 7) * 8;
      *(uint4*)&Kls[0][row * 72 + cb] = *(const uint4*)(khb + (size_t)(mt + row) * DHH + cb);
      *(uint4*)&Kls[1][row * 72 + cb] = *(const uint4*)(klb + (size_t)(mt + row) * DHH + cb);
    }
    __syncthreads();
    f32x4 acc[2][2] = {};
#pragma unroll
    for (int ks = 0; ks < 2; ks++) {
      bf16x8 bh2[2], bl2[2];
#pragma unroll
      for (int cf = 0; cf < 2; cf++) {
        int row = w * 32 + cf * 16 + m15;
        bh2[cf] = *(const bf16x8*)&Kls[0][row * 72 + ks * 32 + kg * 8];
        bl2[cf] = *(const bf16x8*)&Kls[1][row * 72 + ks * 32 + kg * 8];
      }
#pragma unroll
      for (int rf = 0; rf < 2; rf++)
#pragma unroll
        for (int cf = 0; cf < 2; cf++) {
          acc[rf][cf] = __builtin_amdgcn_mfma_f32_16x16x32_bf16(aqh[rf][ks], bh2[cf], acc[rf][cf], 0, 0, 0);
          acc[rf][cf] = __builtin_amdgcn_mfma_f32_16x16x32_bf16(aql[rf][ks], bh2[cf], acc[rf][cf], 0, 0, 0);
          acc[rf][cf] = __builtin_amdgcn_mfma_f32_16x16x32_bf16(aqh[rf][ks], bl2[cf], acc[rf][cf], 0, 0, 0);
        }
    }
#pragma unroll
    for (int rf = 0; rf < 2; rf++)
#pragma unroll
      for (int cf = 0; cf < 2; cf++) {
        int col = mt + w * 32 + cf * 16 + m15;
#pragma unroll
        for (int rr = 0; rr < 4; rr++)
          S[(srow0 + rf * 16 + kg * 4 + rr) * MEMM + col] = acc[rf][cf][rr] * scale;
      }
  }
}

// ============ kNN path B: exact top-32 per row via bit-serial radix =========
// Lane owns cands {i*256 + lane*4 + e}: 16 dwordx4 loads (1 KB/wave/instr).
// Count: 64 independent VALU adds + 6-step shuffle reduce (R6-measured form).
__global__ __launch_bounds__(256, 4) void knn_select_kernel(const float* __restrict__ S,
                                                            float* __restrict__ topv,
                                                            int* __restrict__ topi,
                                                            int row_base) {
  int lane = threadIdx.x & 63;
  int row = blockIdx.x * 4 + (threadIdx.x >> 6);
  const float* srow = S + (size_t)row * MEMM;
  unsigned u[64];
#pragma unroll
  for (int i = 0; i < 16; i++) {
    uint4 v = *(const uint4*)(srow + i * 256 + lane * 4);
    unsigned vs[4] = {v.x, v.y, v.z, v.w};
#pragma unroll
    for (int e = 0; e < 4; e++) {
      unsigned bb = vs[e];
      u[i * 4 + e] = (bb & 0x80000000u) ? ~bb : (bb | 0x80000000u);
    }
  }
  unsigned T = 0;
#pragma unroll 1
  for (int bit = 31; bit >= 0; --bit) {
    unsigned Tp = T | (1u << bit);
    int c = 0;
#pragma unroll
    for (int j = 0; j < 64; j++) c += (u[j] >= Tp) ? 1 : 0;
#pragma unroll
    for (int m = 32; m; m >>= 1) c += __shfl_xor(c, m, 64);
    if (c >= TOPKK) {
      T = Tp;
      if (c == TOPKK) break;
    }
  }
  unsigned long long below = (1ull << lane) - 1ull;
  float* tvrow = topv + (size_t)(row_base + row) * TOPKK;
  int* tirow = topi + (size_t)(row_base + row) * TOPKK;
  int g = 0;
#pragma unroll
  for (int i = 0; i < 16; i++)
#pragma unroll
    for (int e = 0; e < 4; e++) {
      int j = i * 4 + e;
      bool f = u[j] > T;
      unsigned long long m = __ballot(f);
      if (f) {
        int pos = g + __popcll(m & below);
        union { unsigned b; float f2; } rv;
        rv.b = (u[j] & 0x80000000u) ? (u[j] & 0x7fffffffu) : ~u[j];
        tvrow[pos] = rv.f2;
        tirow[pos] = i * 256 + lane * 4 + e;
      }
      g += __popcll(m);
    }
#pragma unroll 1
  for (int i = 0; i < 16 && g < TOPKK; i++)
#pragma unroll
    for (int e = 0; e < 4; e++) {
      int j = i * 4 + e;
      bool f = (u[j] == T);
      unsigned long long m = __ballot(f);
      if (f) {
        int pos = g + __popcll(m & below);
        if (pos < TOPKK) {
          union { unsigned b; float f2; } rv;
          rv.b = (T & 0x80000000u) ? (T & 0x7fffffffu) : ~T;
          tvrow[pos] = rv.f2;
          tirow[pos] = i * 256 + lane * 4 + e;
        }
      }
      g += __popcll(m);
    }
}

// ---------------- top-32 insert helper (fused fallback only) ----------------
__device__ __forceinline__ void insert32vi(float (&rtv)[32], int (&rti)[32],
                                           float sv, int idx, float& thr) {
  float mv = rtv[0], mv2 = INFINITY;
  int mi = 0;
#pragma unroll
  for (int k = 1; k < 32; k++) {
    float v = rtv[k];
    bool lt = v < mv;
    mv2 = lt ? mv : fminf(mv2, v);
    mv = lt ? v : mv;
    mi = lt ? k : mi;
  }
#pragma unroll
  for (int k = 0; k < 32; k++) {
    bool hit = (k == mi);
    rtv[k] = hit ? sv : rtv[k];
    rti[k] = hit ? idx : rti[k];
  }
  thr = fminf(mv2, sv);
}

// ============ fused MFMA score GEMM + top-32 (FALLBACK, tiny ws) ===========
__global__ __launch_bounds__(256) void knn_mfma_topk(const float* __restrict__ q,
                                                     const __bf16* __restrict__ khi,
                                                     const __bf16* __restrict__ klo,
                                                     float* __restrict__ topv,
                                                     int* __restrict__ topi) {
  __shared__ __bf16 Kls[2][128 * 72];
  __shared__ float scb[32][132];
  __shared__ unsigned short midx[32 * 260];
  __shared__ float rthr[8][32];
  int it = blockIdx.x, h = blockIdx.y, b = blockIdx.z;
  int t = threadIdx.x;
  int lane = t & 63, w = t >> 6;
  int m15 = lane & 15, kg = lane >> 4;
  const float scale = 0.125f;
  bf16x8 aqh[2][2], aql[2][2];
#pragma unroll
  for (int rf = 0; rf < 2; rf++)
#pragma unroll
    for (int ks = 0; ks < 2; ks++) {
      const float* qp = q + ((size_t)(b * NN) + it * 32 + rf * 16 + m15) * QKVS +
                        h * DHH + ks * 32 + kg * 8;
      float4 x0 = *(const float4*)qp;
      float4 x1 = *(const float4*)(qp + 4);
      float xs[8] = {x0.x, x0.y, x0.z, x0.w, x1.x, x1.y, x1.z, x1.w};
#pragma unroll
      for (int e = 0; e < 8; e++) {
        __bf16 hv = (__bf16)xs[e];
        aqh[rf][ks][e] = hv;
        aql[rf][ks][e] = (__bf16)(xs[e] - (float)hv);
      }
    }
  int r = t & 31, p = t >> 5;
  rthr[p][r] = -INFINITY;
  float rtv[32]; int rti[32];
#pragma unroll
  for (int k = 0; k < 32; k++) { rtv[k] = -INFINITY; rti[k] = 0; }
  float thr = -INFINITY;
  const __bf16* khb = khi + (size_t)b * MEMM * DHH;
  const __bf16* klb = klo + (size_t)b * MEMM * DHH;

  for (int mt = 0; mt < MEMM; mt += 128) {
    __syncthreads();
#pragma unroll
    for (int i = 0; i < 4; i++) {
      int lin = i * 256 + t;
      int row = lin >> 3, cb = (lin & 7) * 8;
      *(uint4*)&Kls[0][row * 72 + cb] = *(const uint4*)(khb + (size_t)(mt + row) * DHH + cb);
      *(uint4*)&Kls[1][row * 72 + cb] = *(const uint4*)(klb + (size_t)(mt + row) * DHH + cb);
    }
    __syncthreads();
    f32x4 acc[2][2] = {};
#pragma unroll
    for (int ks = 0; ks < 2; ks++) {
      bf16x8 bh2[2], bl2[2];
#pragma unroll
      for (int cf = 0; cf < 2; cf++) {
        int row = w * 32 + cf * 16 + m15;
        bh2[cf] = *(const bf16x8*)&Kls[0][row * 72 + ks * 32 + kg * 8];
        bl2[cf] = *(const bf16x8*)&Kls[1][row * 72 + ks * 32 + kg * 8];
      }
#pragma unroll
      for (int rf = 0; rf < 2; rf++)
#pragma unroll
        for (int cf = 0; cf < 2; cf++) {
          acc[rf][cf] = __builtin_amdgcn_mfma_f32_16x16x32_bf16(aqh[rf][ks], bh2[cf], acc[rf][cf], 0, 0, 0);
          acc[rf][cf] = __builtin_amdgcn_mfma_f32_16x16x32_bf16(aql[rf][ks], bh2[cf], acc[rf][cf], 0, 0, 0);
          acc[rf][cf] = __builtin_amdgcn_mfma_f32_16x16x32_bf16(aqh[rf][ks], bl2[cf], acc[rf][cf], 0, 0, 0);
        }
    }
#pragma unroll
    for (int rf = 0; rf < 2; rf++)
#pragma unroll
      for (int cf = 0; cf < 2; cf++) {
        int col = w * 32 + cf * 16 + m15;
#pragma unroll
        for (int rr = 0; rr < 4; rr++)
          scb[rf * 16 + kg * 4 + rr][col] = acc[rf][cf][rr] * scale;
      }
    __syncthreads();
    {
      float B2 = rthr[0][r];
#pragma unroll
      for (int j = 1; j < 8; j++) B2 = fmaxf(B2, rthr[j][r]);
      const float* srow = &scb[r][16 * p];
#pragma unroll 1
      for (int c = 0; c < 16; c++) {
        int cc = (c + r) & 15;
        float sv = srow[cc];
        if (sv > fmaxf(thr, B2))
          insert32vi(rtv, rti, sv, mt + 16 * p + cc, thr);
      }
      rthr[p][r] = thr;
    }
  }
  __syncthreads();
  float* mvals = (float*)&Kls[0][0];
#pragma unroll
  for (int k = 0; k < 32; k++) {
    int cc = (k + r) & 31;
    mvals[(size_t)260 * r + 32 * p + cc] = rtv[k];
    midx[(size_t)260 * r + 32 * p + cc] = (unsigned short)rti[k];
  }
  __syncthreads();
  if (t < 32) {
#pragma unroll 1
    for (int c = 0; c < 224; c++) {
      int cc = c + r; if (cc >= 224) cc -= 224;
      float sv = mvals[(size_t)260 * r + 32 + cc];
      if (sv > thr)
        insert32vi(rtv, rti, sv, (int)midx[(size_t)260 * r + 32 + cc], thr);
    }
    size_t rowg = ((size_t)b * HH + h) * NN + it * 32 + r;
#pragma unroll
    for (int k = 0; k < 32; k++) {
      topv[rowg * TOPKK + k] = rtv[k];
      topi[rowg * TOPKK + k] = rti[k];
    }
  }
}

// ======== MFMA flash attention (compensated bf16, swapped QK^T layout) =====
// 1-D grid 512: flat = bi*64 + (b*8+h) -> blocks of one (b,h) co-locate on
// one XCD (L2 reuse of K/V). K/V tile jt+1 prefetched to regs (T14).
__global__ __launch_bounds__(256) void attn_mfma_kernel(
    const float* __restrict__ qkv,
    const __bf16* __restrict__ vth, const __bf16* __restrict__ vtl,
    __bf16* __restrict__ ao, const float* __restrict__ topv,
    const int* __restrict__ topi, const float* __restrict__ mem_v, int knn) {
  __shared__ __align__(16) __bf16 smem[27648];   // 55296 B
  __bf16* Kh = smem;                 // [64][72]
  __bf16* Kl = smem + 4608;
  __bf16* Vh = smem + 9216;          // V^T [d 64][72]
  __bf16* Vl = smem + 13824;
  __bf16* Pw = smem + 18432;         // [wave][hi/lo][16][72]

  int flat = blockIdx.x;
  int bi = flat >> 6;
  int hb = flat & 63;
  int h = hb & 7, b = hb >> 3;
  int t = threadIdx.x, lane = t & 63, w = t >> 6;
  int q15 = lane & 15, g = lane >> 4;
  const float scale = 0.125f;

  bf16x8 qh[2], ql[2];
  {
    const float* qp = qkv + ((size_t)(b * NN) + bi * 64 + w * 16 + q15) * QKVS + h * DHH;
#pragma unroll
    for (int ks = 0; ks < 2; ks++) {
      float4 x0 = *(const float4*)(qp + ks * 32 + g * 8);
      float4 x1 = *(const float4*)(qp + ks * 32 + g * 8 + 4);
      float xs[8] = {x0.x, x0.y, x0.z, x0.w, x1.x, x1.y, x1.z, x1.w};
#pragma unroll
      for (int e = 0; e < 8; e++) {
        __bf16 hv = (__bf16)xs[e];
        qh[ks][e] = hv;
        ql[ks][e] = (__bf16)(xs[e] - (float)hv);
      }
    }
  }
  int tr = t >> 4, kc = (t & 15) * 4;      // K: rows tr, tr+16, tr+32, tr+48
  int td = t >> 3, tb = (t & 7) * 8;       // V: rows td, td+32
  float4 kp0, kp1, kp2, kp3;
  uint4 vhp0, vhp1, vlp0, vlp1;

#define LOAD_TILE(jt_) do {                                                        \
    const float* kb_ = qkv + ((size_t)(b * NN) + (jt_) * 64 + tr) * QKVS + 512 +   \
                       h * DHH + kc;                                               \
    kp0 = *(const float4*)kb_;                                                     \
    kp1 = *(const float4*)(kb_ + (size_t)16 * QKVS);                               \
    kp2 = *(const float4*)(kb_ + (size_t)32 * QKVS);                               \
    kp3 = *(const float4*)(kb_ + (size_t)48 * QKVS);                               \
    size_t vb_ = ((size_t)(b * HH + h) * 64 + td) * NN + (jt_) * 64 + tb;          \
    vhp0 = *(const uint4*)(vth + vb_);                                             \
    vhp1 = *(const uint4*)(vth + vb_ + (size_t)32 * NN);                           \
    vlp0 = *(const uint4*)(vtl + vb_);                                             \
    vlp1 = *(const uint4*)(vtl + vb_ + (size_t)32 * NN);                           \
  } while (0)

#define STORE_K(kp_, ro_) do {                                                     \
    bf16x4 hv_, lv_;                                                               \
    float e0_ = kp_.x, e1_ = kp_.y, e2_ = kp_.z, e3_ = kp_.w;                      \
    hv_[0] = (__bf16)e0_; lv_[0] = (__bf16)(e0_ - (float)hv_[0]);                  \
    hv_[1] = (__bf16)e1_; lv_[1] = (__bf16)(e1_ - (float)hv_[1]);                  \
    hv_[2] = (__bf16)e2_; lv_[2] = (__bf16)(e2_ - (float)hv_[2]);                  \
    hv_[3] = (__bf16)e3_; lv_[3] = (__bf16)(e3_ - (float)hv_[3]);                  \
    *(bf16x4*)&Kh[((ro_) + tr) * 72 + kc] = hv_;                                   \
    *(bf16x4*)&Kl[((ro_) + tr) * 72 + kc] = lv_;                                   \
  } while (0)

  float m_run = -INFINITY, l_run = 0.f;
  f32x4 opv[4] = {};
  int ntiles = bi + 1;
  LOAD_TILE(0);
  for (int jt = 0; jt < ntiles; jt++) {
    __syncthreads();
    STORE_K(kp0, 0); STORE_K(kp1, 16); STORE_K(kp2, 32); STORE_K(kp3, 48);
    *(uint4*)&Vh[td * 72 + tb] = vhp0;
    *(uint4*)&Vh[(32 + td) * 72 + tb] = vhp1;
    *(uint4*)&Vl[td * 72 + tb] = vlp0;
    *(uint4*)&Vl[(32 + td) * 72 + tb] = vlp1;
    if (jt + 1 < ntiles) LOAD_TILE(jt + 1);
    __syncthreads();
    int smax = (jt == bi) ? w : 3;
    float sc16[16];
    float tmax = -INFINITY;
#pragma unroll
    for (int s = 0; s < 4; s++) {
      if (s <= smax) {
        f32x4 accs = {};
#pragma unroll
        for (int ks = 0; ks < 2; ks++) {
          bf16x8 ah = *(const bf16x8*)&Kh[(s * 16 + q15) * 72 + ks * 32 + g * 8];
          bf16x8 al = *(const bf16x8*)&Kl[(s * 16 + q15) * 72 + ks * 32 + g * 8];
          accs = __builtin_amdgcn_mfma_f32_16x16x32_bf16(ah, qh[ks], accs, 0, 0, 0);
          accs = __builtin_amdgcn_mfma_f32_16x16x32_bf16(al, qh[ks], accs, 0, 0, 0);
          accs = __builtin_amdgcn_mfma_f32_16x16x32_bf16(ah, ql[ks], accs, 0, 0, 0);
        }
#pragma unroll
        for (int r = 0; r < 4; r++) {
          float sv = accs[r] * scale;
          if (jt == bi) {
            int kvg = jt * 64 + s * 16 + g * 4 + r;
            int qg = bi * 64 + w * 16 + q15;
            if (kvg > qg) sv = -INFINITY;
          }
          sc16[s * 4 + r] = sv;
          tmax = fmaxf(tmax, sv);
        }
      } else {
#pragma unroll
        for (int r = 0; r < 4; r++) sc16[s * 4 + r] = -INFINITY;
      }
    }
    tmax = fmaxf(tmax, __shfl_xor(tmax, 16, 64));
    tmax = fmaxf(tmax, __shfl_xor(tmax, 32, 64));
    float m_new = fmaxf(m_run, tmax);
    float psum = 0.f;
    __bf16 ph[16], pl[16];
#pragma unroll
    for (int i = 0; i < 16; i++) {
      float p = __expf(sc16[i] - m_new);
      psum += p;
      __bf16 hp = (__bf16)p;
      ph[i] = hp; pl[i] = (__bf16)(p - (float)hp);
    }
    psum += __shfl_xor(psum, 16, 64);
    psum += __shfl_xor(psum, 32, 64);
    float alpha = __expf(m_run - m_new);
    l_run = l_run * alpha + psum;
    m_run = m_new;
    __bf16* Ph = Pw + (w * 2 + 0) * 1152;
    __bf16* Pl = Pw + (w * 2 + 1) * 1152;
#pragma unroll
    for (int s = 0; s < 4; s++) {
      bf16x4 hv, lv;
#pragma unroll
      for (int r = 0; r < 4; r++) { hv[r] = ph[s * 4 + r]; lv[r] = pl[s * 4 + r]; }
      *(bf16x4*)&Ph[q15 * 72 + s * 16 + g * 4] = hv;
      *(bf16x4*)&Pl[q15 * 72 + s * 16 + g * 4] = lv;
    }
    __builtin_amdgcn_wave_barrier();
    float a0 = __shfl(alpha, g * 4 + 0, 64);
    float a1 = __shfl(alpha, g * 4 + 1, 64);
    float a2 = __shfl(alpha, g * 4 + 2, 64);
    float a3 = __shfl(alpha, g * 4 + 3, 64);
#pragma unroll
    for (int dsub = 0; dsub < 4; dsub++) {
      opv[dsub][0] *= a0; opv[dsub][1] *= a1;
      opv[dsub][2] *= a2; opv[dsub][3] *= a3;
    }
#pragma unroll
    for (int ks2 = 0; ks2 < 2; ks2++) {
      bf16x8 pah = *(const bf16x8*)&Ph[q15 * 72 + ks2 * 32 + g * 8];
      bf16x8 pal = *(const bf16x8*)&Pl[q15 * 72 + ks2 * 32 + g * 8];
#pragma unroll
      for (int dsub = 0; dsub < 4; dsub++) {
        bf16x8 vbh = *(const bf16x8*)&Vh[(dsub * 16 + q15) * 72 + ks2 * 32 + g * 8];
        bf16x8 vbl = *(const bf16x8*)&Vl[(dsub * 16 + q15) * 72 + ks2 * 32 + g * 8];
        opv[dsub] = __builtin_amdgcn_mfma_f32_16x16x32_bf16(pah, vbh, opv[dsub], 0, 0, 0);
        opv[dsub] = __builtin_amdgcn_mfma_f32_16x16x32_bf16(pal, vbh, opv[dsub], 0, 0, 0);
        opv[dsub] = __builtin_amdgcn_mfma_f32_16x16x32_bf16(pah, vbl, opv[dsub], 0, 0, 0);
      }
    }
  }
#undef LOAD_TILE
#undef STORE_K
  __syncthreads();
  float* scf  = (float*)smem;                 // [64][68] fp32
  float* marr = (float*)(smem + 8704);
  float* larr = marr + 64;
  float* aarr = marr + 128;
  float* sc2  = (float*)(smem + 9216);        // [64][33] fp32
  int*   pidx = (int*)(smem + 13824);         // [64][32] int
#pragma unroll
  for (int dsub = 0; dsub < 4; dsub++)
#pragma unroll
    for (int r = 0; r < 4; r++)
      scf[(w * 16 + g * 4 + r) * 68 + dsub * 16 + q15] = opv[dsub][r];
  if (g == 0) { marr[w * 16 + q15] = m_run; larr[w * 16 + q15] = l_run; }
  __syncthreads();
  int r_ = t & 63, w4 = t >> 6;
  float acc16[16];
  if (knn) {
    size_t rowbase = ((size_t)b * HH + h) * NN + bi * 64;
    for (int rr = w * 16; rr < w * 16 + 16; rr++) {
      float s = (lane < TOPKK) ? topv[(rowbase + rr) * TOPKK + lane] : -INFINITY;
      float m_old = marr[rr];
      float tm = s;
#pragma unroll
      for (int m = 32; m; m >>= 1) tm = fmaxf(tm, __shfl_xor(tm, m, 64));
      float m_new = fmaxf(m_old, tm);
      float p = __expf(s - m_new);
      float ts = p;
#pragma unroll
      for (int m = 32; m; m >>= 1) ts += __shfl_xor(ts, m, 64);
      float alpha = __expf(m_old - m_new);
      if (lane < TOPKK) {
        sc2[rr * 33 + lane] = p;
        pidx[rr * 32 + lane] = topi[(rowbase + rr) * TOPKK + lane];
      }
      if (lane == 0) {
        marr[rr] = m_new; larr[rr] = larr[rr] * alpha + ts; aarr[rr] = alpha;
      }
    }
    __syncthreads();
    float al = aarr[r_];
#pragma unroll
    for (int dd = 0; dd < 16; dd++) acc16[dd] = scf[r_ * 68 + w4 * 16 + dd] * al;
    const float* mvb = mem_v + (size_t)b * MEMM * DHH;
#pragma unroll 1
    for (int kk = 0; kk < TOPKK; kk++) {
      float p = sc2[r_ * 33 + kk];
      const float* mrow = mvb + (size_t)pidx[r_ * 32 + kk] * DHH + w4 * 16;
#pragma unroll
      for (int dd = 0; dd < 16; dd += 4) {
        float4 m4 = *(const float4*)(mrow + dd);
        acc16[dd] += p * m4.x; acc16[dd + 1] += p * m4.y;
        acc16[dd + 2] += p * m4.z; acc16[dd + 3] += p * m4.w;
      }
    }
  } else {
#pragma unroll
    for (int dd = 0; dd < 16; dd++) acc16[dd] = scf[r_ * 68 + w4 * 16 + dd];
  }
  float linv = 1.f / larr[r_];
  bf16x8 o0, o1;
#pragma unroll
  for (int j = 0; j < 8; j++) {
    o0[j] = (__bf16)(acc16[j] * linv);
    o1[j] = (__bf16)(acc16[8 + j] * linv);
  }
  __bf16* aop = ao + ((size_t)(b * NN) + bi * 64 + r_) * DD + h * DHH + w4 * 16;
  *(bf16x8*)aop = o0;
  *(bf16x8*)(aop + 8) = o1;
}

// ---------------- host ----------------
extern "C" void kernel_launch(void* const* d_in, const int* in_sizes, int n_in,
                              void* d_out, int out_size, void* d_ws, size_t ws_size,
                              hipStream_t stream) {
  const float* x_in  = (const float*)d_in[0];
  const float* Wq    = (const float*)d_in[1];
  const float* Wk    = (const float*)d_in[2];
  const float* Wv    = (const float*)d_in[3];
  const float* Wo    = (const float*)d_in[4];
  const float* ln1_s = (const float*)d_in[5];
  const float* ln1_b = (const float*)d_in[6];
  const float* ln2_s = (const float*)d_in[7];
  const float* ln2_b = (const float*)d_in[8];
  const float* W1    = (const float*)d_in[9];
  const float* W2    = (const float*)d_in[10];
  const float* lnf_s = (const float*)d_in[11];
  const float* lnf_b = (const float*)d_in[12];
  const float* mem_k = (const float*)d_in[13];
  const float* mem_v = (const float*)d_in[14];

  float* ws  = (float*)d_ws;
  float*  xb    = ws;
  float*  qkvb  = ws + 2097152;           // [4096][1536] fp32
  __bf16* hb16  = (__bf16*)(ws + 8388608);
  __bf16* ao16  = (__bf16*)(ws + 9437184);
  __bf16* wqT   = (__bf16*)(ws + 10485760);   // wq/wk/wv contiguous [1536][512]
  __bf16* woT   = (__bf16*)(ws + 10878976);
  __bf16* w1T   = (__bf16*)(ws + 11010048);
  __bf16* w2T   = (__bf16*)(ws + 11534336);
  float*  tvb   = ws + 12058624;
  int*    tib   = (int*)(ws + 13107200);
  __bf16* ffb16 = (__bf16*)(ws + 2097152);    // aliases qkvb (dead post-attn)
  __bf16* wkT   = wqT + 262144;
  __bf16* wvT   = wqT + 524288;
  __bf16* khi16 = (__bf16*)(ws + 8388608);
  __bf16* klo16 = (__bf16*)(ws + 9437184);

  // S chunk region after base layout; V^T hi/lo overlap it (lifetime-disjoint).
  const size_t base_floats = 14155776;
  const size_t slice_floats = (size_t)NN * MEMM;
  const size_t ws_floats = ws_size / sizeof(float);
  int nbh = 0;
  for (int c = 64; c >= 1; c >>= 1) {
    if (base_floats + (size_t)c * slice_floats <= ws_floats) { nbh = c; break; }
  }
  float* Sb = ws + base_floats;
  __bf16* vth = (__bf16*)(ws + base_floats);
  __bf16* vtl = (__bf16*)(ws + base_floats + 1048576);

  dim3 blk(256);
  const size_t DD2 = (size_t)DD * DD;
  for (int l = 0; l < DEPTHH; l++) {
    const float* xcur = (l == 0) ? x_in : xb;
    transpose_all_kernel<<<dim3(3072), blk, 0, stream>>>(
        Wq + l * DD2, Wk + l * DD2, Wv + l * DD2, Wo + l * DD2,
        W1 + (size_t)l * DD * FFF, W2 + (size_t)l * FFF * DD,
        wqT, wkT, wvT, woT, w1T, w2T);

    ln_kernel<1><<<NT, blk, 0, stream>>>(xcur, ln1_s + l * DD, ln1_b + l * DD, hb16);
    gemm_mfma64<0, 0><<<dim3(24, 32), blk, 0, stream>>>(hb16, wqT, nullptr, qkvb, NT, QKVS, DD);
    int mi = (l == 3) ? 0 : ((l == 4) ? 1 : -1);
    if (mi >= 0) {
      const float* mk = mem_k + (size_t)mi * BB * MEMM * DHH;
      split_bf16_kernel<<<dim3(BB * MEMM * DHH / 1024), blk, 0, stream>>>(mk, khi16, klo16);
      if (nbh > 0) {
        for (int bh0 = 0; bh0 < BB * HH; bh0 += nbh) {
          knn_score_mfma<<<dim3(16, nbh, MSPLIT), blk, 0, stream>>>(qkvb, khi16, klo16, Sb, bh0);
          knn_select_kernel<<<dim3(nbh * NN / 4), blk, 0, stream>>>(Sb, tvb, tib, bh0 * NN);
        }
      } else {
        knn_mfma_topk<<<dim3(16, 8, 8), blk, 0, stream>>>(qkvb, khi16, klo16, tvb, tib);
      }
    }
    vtrans_split_kernel<<<dim3(8, 8, 8), blk, 0, stream>>>(qkvb, vth, vtl);
    attn_mfma_kernel<<<dim3(512), blk, 0, stream>>>(
        qkvb, vth, vtl, ao16, tvb, tib,
        mem_v + (size_t)(mi < 0 ? 0 : mi) * BB * MEMM * DHH, mi >= 0 ? 1 : 0);
    gemm_mfma64<2, 0><<<dim3(8, 32), blk, 0, stream>>>(ao16, woT, xcur, xb, NT, DD, DD);
    ln_kernel<1><<<NT, blk, 0, stream>>>(xb, ln2_s + l * DD, ln2_b + l * DD, hb16);
    gemm_mfma128<1, 1><<<dim3(16, 32), blk, 0, stream>>>(hb16, w1T, nullptr, ffb16, NT, FFF, DD);
    gemm_mfma64<2, 0><<<dim3(8, 32), blk, 0, stream>>>(ffb16, w2T, xb, xb, NT, DD, FFF);
  }
  ln_kernel<0><<<NT, blk, 0, stream>>>(xb, lnf_s, lnf_b, (float*)d_out);
}

// Round 11
// 1894.546 us; speedup vs baseline: 1.1248x; 1.0197x over previous
//
#include <hip/hip_runtime.h>
#include <math.h>

#define BB 8
#define NN 512
#define DD 512
#define HH 8
#define DHH 64
#define FFF 2048
#define MEMM 4096
#define TOPKK 32
#define DEPTHH 6
#define NT (BB*NN)   /* 4096 tokens */
#define QKVS 1536    /* fused qkv row stride */

typedef __bf16 bf16x8 __attribute__((ext_vector_type(8)));
typedef __bf16 bf16x4 __attribute__((ext_vector_type(4)));
typedef float f32x4 __attribute__((ext_vector_type(4)));

// ---------------- LayerNorm (fp32 in, fp32 or bf16 out) ----------------
template <int OBF16>
__global__ __launch_bounds__(256) void ln_kernel(const float* __restrict__ xin,
                                                 const float* __restrict__ g,
                                                 const float* __restrict__ bt,
                                                 void* __restrict__ outv) {
  __shared__ float red[4];
  int tok = blockIdx.x;
  const float* xr = xin + (size_t)tok * DD;
  int t = threadIdx.x;
  float v0 = xr[t], v1 = xr[t + 256];
  float s = v0 + v1;
#pragma unroll
  for (int m = 32; m; m >>= 1) s += __shfl_xor(s, m, 64);
  if ((t & 63) == 0) red[t >> 6] = s;
  __syncthreads();
  float mean = (red[0] + red[1] + red[2] + red[3]) * (1.0f / 512.0f);
  float d0 = v0 - mean, d1 = v1 - mean;
  float vv = d0 * d0 + d1 * d1;
#pragma unroll
  for (int m = 32; m; m >>= 1) vv += __shfl_xor(vv, m, 64);
  __syncthreads();
  if ((t & 63) == 0) red[t >> 6] = vv;
  __syncthreads();
  float var = (red[0] + red[1] + red[2] + red[3]) * (1.0f / 512.0f);
  float inv = rsqrtf(var + 1e-5f);
  float o0 = d0 * inv * g[t] + bt[t];
  float o1 = d1 * inv * g[t + 256] + bt[t + 256];
  if (OBF16) {
    __bf16* out = (__bf16*)outv;
    out[(size_t)tok * DD + t] = (__bf16)o0;
    out[(size_t)tok * DD + t + 256] = (__bf16)o1;
  } else {
    float* out = (float*)outv;
    out[(size_t)tok * DD + t] = o0;
    out[(size_t)tok * DD + t + 256] = o1;
  }
}

__device__ inline float gelu_f(float x) {
  float x3 = x * x * x;
  return 0.5f * x * (1.0f + tanhf(0.7978845608028654f * (x + 0.044715f * x3)));
}

// --------- batched weight transpose+convert: all 6 weights, one launch ------
__global__ __launch_bounds__(256) void transpose_all_kernel(
    const float* __restrict__ Wq, const float* __restrict__ Wk,
    const float* __restrict__ Wv, const float* __restrict__ Wo,
    const float* __restrict__ W1, const float* __restrict__ W2,
    __bf16* __restrict__ wqT, __bf16* __restrict__ wkT,
    __bf16* __restrict__ wvT, __bf16* __restrict__ woT,
    __bf16* __restrict__ w1T, __bf16* __restrict__ w2T) {
  __shared__ float tile[32][33];
  int tid = blockIdx.x;
  const float* src; __bf16* dst; int K, N, tt;
  if (tid < 1024) {
    int which = tid >> 8; tt = tid & 255; K = 512; N = 512;
    src = (which == 0) ? Wq : (which == 1) ? Wk : (which == 2) ? Wv : Wo;
    dst = (which == 0) ? wqT : (which == 1) ? wkT : (which == 2) ? wvT : woT;
  } else if (tid < 2048) {
    tt = tid - 1024; K = 512; N = 2048; src = W1; dst = w1T;
  } else {
    tt = tid - 2048; K = 2048; N = 512; src = W2; dst = w2T;
  }
  int nx = N >> 5;
  int n0 = (tt % nx) * 32, k0 = (tt / nx) * 32;
  int tx = threadIdx.x & 31, ty = threadIdx.x >> 5;
#pragma unroll
  for (int i = 0; i < 4; i++) {
    int r = ty + i * 8;
    tile[r][tx] = src[(size_t)(k0 + r) * N + n0 + tx];
  }
  __syncthreads();
#pragma unroll
  for (int i = 0; i < 4; i++) {
    int r = ty + i * 8;
    dst[(size_t)(n0 + r) * K + k0 + tx] = (__bf16)tile[tx][r];
  }
}

// -------- async global->LDS 16B helper (wave-uniform lds base + lane*16) ----
__device__ __forceinline__ void gload16(const __bf16* g, __bf16* lds) {
  __builtin_amdgcn_global_load_lds(
      (const __attribute__((address_space(1))) void*)g,
      (__attribute__((address_space(3))) void*)lds, 16, 0, 0);
}

// ------- bf16 MFMA GEMM, 128x128 tile (for wide-N: FF1) --------------------
template <int EPI, int OBF16>
__global__ __launch_bounds__(256) void gemm_mfma128(const __bf16* __restrict__ A,
                                                    const __bf16* __restrict__ Bt,
                                                    const float* __restrict__ R,
                                                    void* __restrict__ Cout,
                                                    int M, int N, int K) {
  __shared__ __align__(16) __bf16 Als[128 * 64];
  __shared__ __align__(16) __bf16 Bls[128 * 64];
  int t = threadIdx.x;
  int bn = blockIdx.x, bm = blockIdx.y;
  int lane = t & 63, w = t >> 6;
  int wr = w >> 1, wc = w & 1;
  int m15 = lane & 15, q = lane >> 4;
  f32x4 acc[4][4] = {};
  for (int kt = 0; kt < K; kt += 64) {
    __syncthreads();
#pragma unroll
    for (int i = 0; i < 4; i++) {
      int rg = w * 32 + i * 8;
      int row = rg + (lane >> 3);
      int lcol = (lane & 7) * 8;
      gload16(A + (size_t)(bm * 128 + row) * K + kt + lcol, &Als[rg * 64]);
      gload16(Bt + (size_t)(bn * 128 + row) * K + kt + lcol, &Bls[rg * 64]);
    }
    __syncthreads();
#pragma unroll
    for (int ks = 0; ks < 2; ks++) {
      bf16x8 af[4], bfr[4];
#pragma unroll
      for (int mt = 0; mt < 4; mt++)
        af[mt] = *(const bf16x8*)&Als[(wr * 64 + mt * 16 + m15) * 64 + (ks * 4 + q) * 8];
#pragma unroll
      for (int nt = 0; nt < 4; nt++)
        bfr[nt] = *(const bf16x8*)&Bls[(wc * 64 + nt * 16 + m15) * 64 + (ks * 4 + q) * 8];
#pragma unroll
      for (int mt = 0; mt < 4; mt++)
#pragma unroll
        for (int nt = 0; nt < 4; nt++)
          acc[mt][nt] = __builtin_amdgcn_mfma_f32_16x16x32_bf16(af[mt], bfr[nt],
                                                                acc[mt][nt], 0, 0, 0);
    }
  }
#pragma unroll
  for (int mt = 0; mt < 4; mt++) {
#pragma unroll
    for (int nt = 0; nt < 4; nt++) {
      int gc = bn * 128 + wc * 64 + nt * 16 + m15;
#pragma unroll
      for (int r = 0; r < 4; r++) {
        int gr = bm * 128 + wr * 64 + mt * 16 + q * 4 + r;
        size_t off = (size_t)gr * N + gc;
        float v = acc[mt][nt][r];
        if (EPI == 1) v = gelu_f(v);
        if (EPI == 2) v += R[off];
        if (OBF16) ((__bf16*)Cout)[off] = (__bf16)v;
        else       ((float*)Cout)[off] = v;
      }
    }
  }
}

// ------- bf16 MFMA GEMM, 128x64 tile (for narrow-N: QKV/Wo/FF2 grid fill) --
template <int EPI, int OBF16>
__global__ __launch_bounds__(256) void gemm_mfma64(const __bf16* __restrict__ A,
                                                   const __bf16* __restrict__ Bt,
                                                   const float* __restrict__ R,
                                                   void* __restrict__ Cout,
                                                   int M, int N, int K) {
  __shared__ __align__(16) __bf16 Als[128 * 64];
  __shared__ __align__(16) __bf16 Bls[64 * 64];
  int t = threadIdx.x;
  int bn = blockIdx.x, bm = blockIdx.y;
  int lane = t & 63, w = t >> 6;
  int wr = w >> 1, wc = w & 1;
  int m15 = lane & 15, q = lane >> 4;
  f32x4 acc[4][2] = {};
  for (int kt = 0; kt < K; kt += 64) {
    __syncthreads();
#pragma unroll
    for (int i = 0; i < 4; i++) {
      int rg = w * 32 + i * 8;
      int row = rg + (lane >> 3);
      int lcol = (lane & 7) * 8;
      gload16(A + (size_t)(bm * 128 + row) * K + kt + lcol, &Als[rg * 64]);
    }
#pragma unroll
    for (int i = 0; i < 2; i++) {
      int rg = w * 16 + i * 8;
      int row = rg + (lane >> 3);
      int lcol = (lane & 7) * 8;
      gload16(Bt + (size_t)(bn * 64 + row) * K + kt + lcol, &Bls[rg * 64]);
    }
    __syncthreads();
#pragma unroll
    for (int ks = 0; ks < 2; ks++) {
      bf16x8 af[4], bfr[2];
#pragma unroll
      for (int mt = 0; mt < 4; mt++)
        af[mt] = *(const bf16x8*)&Als[(wr * 64 + mt * 16 + m15) * 64 + (ks * 4 + q) * 8];
#pragma unroll
      for (int nt = 0; nt < 2; nt++)
        bfr[nt] = *(const bf16x8*)&Bls[(wc * 32 + nt * 16 + m15) * 64 + (ks * 4 + q) * 8];
#pragma unroll
      for (int mt = 0; mt < 4; mt++)
#pragma unroll
        for (int nt = 0; nt < 2; nt++)
          acc[mt][nt] = __builtin_amdgcn_mfma_f32_16x16x32_bf16(af[mt], bfr[nt],
                                                                acc[mt][nt], 0, 0, 0);
    }
  }
#pragma unroll
  for (int mt = 0; mt < 4; mt++) {
#pragma unroll
    for (int nt = 0; nt < 2; nt++) {
      int gc = bn * 64 + wc * 32 + nt * 16 + m15;
#pragma unroll
      for (int r = 0; r < 4; r++) {
        int gr = bm * 128 + wr * 64 + mt * 16 + q * 4 + r;
        size_t off = (size_t)gr * N + gc;
        float v = acc[mt][nt][r];
        if (EPI == 1) v = gelu_f(v);
        if (EPI == 2) v += R[off];
        if (OBF16) ((__bf16*)Cout)[off] = (__bf16)v;
        else       ((float*)Cout)[off] = v;
      }
    }
  }
}

// -------- split fp32 -> bf16 hi + bf16 lo (exact residual) --------
__global__ __launch_bounds__(256) void split_bf16_kernel(const float* __restrict__ src,
                                                         __bf16* __restrict__ hi,
                                                         __bf16* __restrict__ lo) {
  int i = blockIdx.x * 256 + threadIdx.x;
  float4 v = ((const float4*)src)[i];
  float xs[4] = {v.x, v.y, v.z, v.w};
  bf16x4 hv, lv;
#pragma unroll
  for (int e = 0; e < 4; e++) {
    __bf16 h = (__bf16)xs[e];
    hv[e] = h;
    lv[e] = (__bf16)(xs[e] - (float)h);
  }
  *(bf16x4*)&hi[(size_t)i * 4] = hv;
  *(bf16x4*)&lo[(size_t)i * 4] = lv;
}

// ---- per-head transpose + split: qkv v-part -> vt[b,h][64][512] bf16 ------
__global__ __launch_bounds__(256) void vtrans_split_kernel(const float* __restrict__ qkv,
                                                           __bf16* __restrict__ vth,
                                                           __bf16* __restrict__ vtl) {
  __shared__ float tile[64 * 68];
  int tt = blockIdx.x, h = blockIdx.y, b = blockIdx.z;
  int t = threadIdx.x;
#pragma unroll
  for (int i = 0; i < 4; i++) {
    int lin = i * 256 + t, row = lin >> 4, c = (lin & 15) * 4;
    float4 x = *(const float4*)(qkv + ((size_t)(b * NN) + tt * 64 + row) * QKVS + 1024 + h * DHH + c);
    *(float4*)&tile[row * 68 + c] = x;
  }
  __syncthreads();
  int d = t >> 2, tb = (t & 3) * 16;
  float xs[16];
#pragma unroll
  for (int j = 0; j < 16; j++) xs[j] = tile[(tb + j) * 68 + d];
  bf16x8 h0, h1, l0, l1;
#pragma unroll
  for (int j = 0; j < 8; j++) {
    __bf16 a = (__bf16)xs[j];
    h0[j] = a; l0[j] = (__bf16)(xs[j] - (float)a);
    __bf16 bmv = (__bf16)xs[8 + j];
    h1[j] = bmv; l1[j] = (__bf16)(xs[8 + j] - (float)bmv);
  }
  size_t ob = ((size_t)(b * HH + h) * 64 + d) * NN + tt * 64 + tb;
  *(bf16x8*)(vth + ob) = h0; *(bf16x8*)(vth + ob + 8) = h1;
  *(bf16x8*)(vtl + ob) = l0; *(bf16x8*)(vtl + ob + 8) = l1;
}

// ============ kNN path A: MFMA score GEMM -> S (chunk-local, bf16) =========
// 32 q-rows per block; grid (16, nbh, MSPLIT). S stored as bf16: halves the
// S round-trip (R10: S-traffic = the knn cost; fp32 chunk only half-L3-hit).
#define MSPLIT 4
__global__ __launch_bounds__(256) void knn_score_mfma(const float* __restrict__ q,
                                                      const __bf16* __restrict__ khi,
                                                      const __bf16* __restrict__ klo,
                                                      __bf16* __restrict__ S,
                                                      int bh0) {
  __shared__ __bf16 Kls[2][128 * 72];        // hi / lo staging, stride 72
  int it = blockIdx.x, bh = bh0 + blockIdx.y;
  int mz = blockIdx.z;
  int b = bh >> 3, h = bh & 7;
  int t = threadIdx.x;
  int lane = t & 63, w = t >> 6;
  int m15 = lane & 15, kg = lane >> 4;
  const float scale = 0.125f;

  bf16x8 aqh[2][2], aql[2][2];
#pragma unroll
  for (int rf = 0; rf < 2; rf++)
#pragma unroll
    for (int ks = 0; ks < 2; ks++) {
      const float* qp = q + ((size_t)(b * NN) + it * 32 + rf * 16 + m15) * QKVS +
                        h * DHH + ks * 32 + kg * 8;
      float4 x0 = *(const float4*)qp;
      float4 x1 = *(const float4*)(qp + 4);
      float xs[8] = {x0.x, x0.y, x0.z, x0.w, x1.x, x1.y, x1.z, x1.w};
#pragma unroll
      for (int e = 0; e < 8; e++) {
        __bf16 hv = (__bf16)xs[e];
        aqh[rf][ks][e] = hv;
        aql[rf][ks][e] = (__bf16)(xs[e] - (float)hv);
      }
    }

  const __bf16* khb = khi + (size_t)b * MEMM * DHH;
  const __bf16* klb = klo + (size_t)b * MEMM * DHH;
  size_t srow0 = (size_t)blockIdx.y * NN + it * 32;  // chunk-local row base

  const int mlo = mz * (MEMM / MSPLIT), mhi = mlo + MEMM / MSPLIT;
  for (int mt = mlo; mt < mhi; mt += 128) {
    __syncthreads();
#pragma unroll
    for (int i = 0; i < 4; i++) {
      int lin = i * 256 + t;
      int row = lin >> 3, cb = (lin & 7) * 8;
      *(uint4*)&Kls[0][row * 72 + cb] = *(const uint4*)(khb + (size_t)(mt + row) * DHH + cb);
      *(uint4*)&Kls[1][row * 72 + cb] = *(const uint4*)(klb + (size_t)(mt + row) * DHH + cb);
    }
    __syncthreads();
    f32x4 acc[2][2] = {};
#pragma unroll
    for (int ks = 0; ks < 2; ks++) {
      bf16x8 bh2[2], bl2[2];
#pragma unroll
      for (int cf = 0; cf < 2; cf++) {
        int row = w * 32 + cf * 16 + m15;
        bh2[cf] = *(const bf16x8*)&Kls[0][row * 72 + ks * 32 + kg * 8];
        bl2[cf] = *(const bf16x8*)&Kls[1][row * 72 + ks * 32 + kg * 8];
      }
#pragma unroll
      for (int rf = 0; rf < 2; rf++)
#pragma unroll
        for (int cf = 0; cf < 2; cf++) {
          acc[rf][cf] = __builtin_amdgcn_mfma_f32_16x16x32_bf16(aqh[rf][ks], bh2[cf], acc[rf][cf], 0, 0, 0);
          acc[rf][cf] = __builtin_amdgcn_mfma_f32_16x16x32_bf16(aql[rf][ks], bh2[cf], acc[rf][cf], 0, 0, 0);
          acc[rf][cf] = __builtin_amdgcn_mfma_f32_16x16x32_bf16(aqh[rf][ks], bl2[cf], acc[rf][cf], 0, 0, 0);
        }
    }
#pragma unroll
    for (int rf = 0; rf < 2; rf++)
#pragma unroll
      for (int cf = 0; cf < 2; cf++) {
        int col = mt + w * 32 + cf * 16 + m15;
#pragma unroll
        for (int rr = 0; rr < 4; rr++)
          S[(srow0 + rf * 16 + kg * 4 + rr) * MEMM + col] = (__bf16)(acc[rf][cf][rr] * scale);
      }
  }
}

// ============ kNN path B: exact top-32 per row, 16-bit radix on bf16 S =====
// Lane owns cands {i*512 + lane*8 + e}: 8 uint4 loads (8 bf16 each).
__global__ __launch_bounds__(256, 4) void knn_select_kernel(const __bf16* __restrict__ S,
                                                            float* __restrict__ topv,
                                                            int* __restrict__ topi,
                                                            int row_base) {
  int lane = threadIdx.x & 63;
  int row = blockIdx.x * 4 + (threadIdx.x >> 6);
  const __bf16* srow = S + (size_t)row * MEMM;
  unsigned u[64];
#pragma unroll
  for (int i = 0; i < 8; i++) {
    uint4 v = *(const uint4*)(srow + i * 512 + lane * 8);
    unsigned vs[4] = {v.x, v.y, v.z, v.w};
#pragma unroll
    for (int e2 = 0; e2 < 4; e2++) {
      unsigned lo = vs[e2] & 0xffffu, hi2 = vs[e2] >> 16;
      u[i * 8 + e2 * 2 + 0] = (lo & 0x8000u) ? (~lo & 0xffffu) : (lo | 0x8000u);
      u[i * 8 + e2 * 2 + 1] = (hi2 & 0x8000u) ? (~hi2 & 0xffffu) : (hi2 | 0x8000u);
    }
  }
  unsigned T = 0;
#pragma unroll 1
  for (int bit = 15; bit >= 0; --bit) {
    unsigned Tp = T | (1u << bit);
    int c = 0;
#pragma unroll
    for (int j = 0; j < 64; j++) c += (u[j] >= Tp) ? 1 : 0;
#pragma unroll
    for (int m = 32; m; m >>= 1) c += __shfl_xor(c, m, 64);
    if (c >= TOPKK) {
      T = Tp;
      if (c == TOPKK) break;
    }
  }
  unsigned long long below = (1ull << lane) - 1ull;
  float* tvrow = topv + (size_t)(row_base + row) * TOPKK;
  int* tirow = topi + (size_t)(row_base + row) * TOPKK;
  int g = 0;
#pragma unroll
  for (int i = 0; i < 8; i++)
#pragma unroll
    for (int e = 0; e < 8; e++) {
      int j = i * 8 + e;
      bool f = u[j] > T;
      unsigned long long m = __ballot(f);
      if (f) {
        int pos = g + __popcll(m & below);
        unsigned b16 = (u[j] & 0x8000u) ? (u[j] & 0x7fffu) : (~u[j] & 0xffffu);
        union { unsigned b; float f2; } rv; rv.b = b16 << 16;
        tvrow[pos] = rv.f2;
        tirow[pos] = i * 512 + lane * 8 + e;
      }
      g += __popcll(m);
    }
#pragma unroll 1
  for (int i = 0; i < 8 && g < TOPKK; i++)
#pragma unroll
    for (int e = 0; e < 8; e++) {
      int j = i * 8 + e;
      bool f = (u[j] == T);
      unsigned long long m = __ballot(f);
      if (f) {
        int pos = g + __popcll(m & below);
        if (pos < TOPKK) {
          unsigned b16 = (T & 0x8000u) ? (T & 0x7fffu) : (~T & 0xffffu);
          union { unsigned b; float f2; } rv; rv.b = b16 << 16;
          tvrow[pos] = rv.f2;
          tirow[pos] = i * 512 + lane * 8 + e;
        }
      }
      g += __popcll(m);
    }
}

// ---------------- top-32 insert helper (fused fallback only) ----------------
__device__ __forceinline__ void insert32vi(float (&rtv)[32], int (&rti)[32],
                                           float sv, int idx, float& thr) {
  float mv = rtv[0], mv2 = INFINITY;
  int mi = 0;
#pragma unroll
  for (int k = 1; k < 32; k++) {
    float v = rtv[k];
    bool lt = v < mv;
    mv2 = lt ? mv : fminf(mv2, v);
    mv = lt ? v : mv;
    mi = lt ? k : mi;
  }
#pragma unroll
  for (int k = 0; k < 32; k++) {
    bool hit = (k == mi);
    rtv[k] = hit ? sv : rtv[k];
    rti[k] = hit ? idx : rti[k];
  }
  thr = fminf(mv2, sv);
}

// ============ fused MFMA score GEMM + top-32 (FALLBACK, tiny ws) ===========
__global__ __launch_bounds__(256) void knn_mfma_topk(const float* __restrict__ q,
                                                     const __bf16* __restrict__ khi,
                                                     const __bf16* __restrict__ klo,
                                                     float* __restrict__ topv,
                                                     int* __restrict__ topi) {
  __shared__ __bf16 Kls[2][128 * 72];
  __shared__ float scb[32][132];
  __shared__ unsigned short midx[32 * 260];
  __shared__ float rthr[8][32];
  int it = blockIdx.x, h = blockIdx.y, b = blockIdx.z;
  int t = threadIdx.x;
  int lane = t & 63, w = t >> 6;
  int m15 = lane & 15, kg = lane >> 4;
  const float scale = 0.125f;
  bf16x8 aqh[2][2], aql[2][2];
#pragma unroll
  for (int rf = 0; rf < 2; rf++)
#pragma unroll
    for (int ks = 0; ks < 2; ks++) {
      const float* qp = q + ((size_t)(b * NN) + it * 32 + rf * 16 + m15) * QKVS +
                        h * DHH + ks * 32 + kg * 8;
      float4 x0 = *(const float4*)qp;
      float4 x1 = *(const float4*)(qp + 4);
      float xs[8] = {x0.x, x0.y, x0.z, x0.w, x1.x, x1.y, x1.z, x1.w};
#pragma unroll
      for (int e = 0; e < 8; e++) {
        __bf16 hv = (__bf16)xs[e];
        aqh[rf][ks][e] = hv;
        aql[rf][ks][e] = (__bf16)(xs[e] - (float)hv);
      }
    }
  int r = t & 31, p = t >> 5;
  rthr[p][r] = -INFINITY;
  float rtv[32]; int rti[32];
#pragma unroll
  for (int k = 0; k < 32; k++) { rtv[k] = -INFINITY; rti[k] = 0; }
  float thr = -INFINITY;
  const __bf16* khb = khi + (size_t)b * MEMM * DHH;
  const __bf16* klb = klo + (size_t)b * MEMM * DHH;

  for (int mt = 0; mt < MEMM; mt += 128) {
    __syncthreads();
#pragma unroll
    for (int i = 0; i < 4; i++) {
      int lin = i * 256 + t;
      int row = lin >> 3, cb = (lin & 7) * 8;
      *(uint4*)&Kls[0][row * 72 + cb] = *(const uint4*)(khb + (size_t)(mt + row) * DHH + cb);
      *(uint4*)&Kls[1][row * 72 + cb] = *(const uint4*)(klb + (size_t)(mt + row) * DHH + cb);
    }
    __syncthreads();
    f32x4 acc[2][2] = {};
#pragma unroll
    for (int ks = 0; ks < 2; ks++) {
      bf16x8 bh2[2], bl2[2];
#pragma unroll
      for (int cf = 0; cf < 2; cf++) {
        int row = w * 32 + cf * 16 + m15;
        bh2[cf] = *(const bf16x8*)&Kls[0][row * 72 + ks * 32 + kg * 8];
        bl2[cf] = *(const bf16x8*)&Kls[1][row * 72 + ks * 32 + kg * 8];
      }
#pragma unroll
      for (int rf = 0; rf < 2; rf++)
#pragma unroll
        for (int cf = 0; cf < 2; cf++) {
          acc[rf][cf] = __builtin_amdgcn_mfma_f32_16x16x32_bf16(aqh[rf][ks], bh2[cf], acc[rf][cf], 0, 0, 0);
          acc[rf][cf] = __builtin_amdgcn_mfma_f32_16x16x32_bf16(aql[rf][ks], bh2[cf], acc[rf][cf], 0, 0, 0);
          acc[rf][cf] = __builtin_amdgcn_mfma_f32_16x16x32_bf16(aqh[rf][ks], bl2[cf], acc[rf][cf], 0, 0, 0);
        }
    }
#pragma unroll
    for (int rf = 0; rf < 2; rf++)
#pragma unroll
      for (int cf = 0; cf < 2; cf++) {
        int col = w * 32 + cf * 16 + m15;
#pragma unroll
        for (int rr = 0; rr < 4; rr++)
          scb[rf * 16 + kg * 4 + rr][col] = acc[rf][cf][rr] * scale;
      }
    __syncthreads();
    {
      float B2 = rthr[0][r];
#pragma unroll
      for (int j = 1; j < 8; j++) B2 = fmaxf(B2, rthr[j][r]);
      const float* srow = &scb[r][16 * p];
#pragma unroll 1
      for (int c = 0; c < 16; c++) {
        int cc = (c + r) & 15;
        float sv = srow[cc];
        if (sv > fmaxf(thr, B2))
          insert32vi(rtv, rti, sv, mt + 16 * p + cc, thr);
      }
      rthr[p][r] = thr;
    }
  }
  __syncthreads();
  float* mvals = (float*)&Kls[0][0];
#pragma unroll
  for (int k = 0; k < 32; k++) {
    int cc = (k + r) & 31;
    mvals[(size_t)260 * r + 32 * p + cc] = rtv[k];
    midx[(size_t)260 * r + 32 * p + cc] = (unsigned short)rti[k];
  }
  __syncthreads();
  if (t < 32) {
#pragma unroll 1
    for (int c = 0; c < 224; c++) {
      int cc = c + r; if (cc >= 224) cc -= 224;
      float sv = mvals[(size_t)260 * r + 32 + cc];
      if (sv > thr)
        insert32vi(rtv, rti, sv, (int)midx[(size_t)260 * r + 32 + cc], thr);
    }
    size_t rowg = ((size_t)b * HH + h) * NN + it * 32 + r;
#pragma unroll
    for (int k = 0; k < 32; k++) {
      topv[rowg * TOPKK + k] = rtv[k];
      topi[rowg * TOPKK + k] = rti[k];
    }
  }
}

// ======== MFMA flash attention (compensated bf16, swapped QK^T layout) =====
// 1-D grid 512: flat = bi*64 + (b*8+h) -> blocks of one (b,h) co-locate on
// one XCD (L2 reuse of K/V). K/V tile jt+1 prefetched to regs (T14).
__global__ __launch_bounds__(256) void attn_mfma_kernel(
    const float* __restrict__ qkv,
    const __bf16* __restrict__ vth, const __bf16* __restrict__ vtl,
    __bf16* __restrict__ ao, const float* __restrict__ topv,
    const int* __restrict__ topi, const float* __restrict__ mem_v, int knn) {
  __shared__ __align__(16) __bf16 smem[27648];   // 55296 B
  __bf16* Kh = smem;                 // [64][72]
  __bf16* Kl = smem + 4608;
  __bf16* Vh = smem + 9216;          // V^T [d 64][72]
  __bf16* Vl = smem + 13824;
  __bf16* Pw = smem + 18432;         // [wave][hi/lo][16][72]

  int flat = blockIdx.x;
  int bi = flat >> 6;
  int hb = flat & 63;
  int h = hb & 7, b = hb >> 3;
  int t = threadIdx.x, lane = t & 63, w = t >> 6;
  int q15 = lane & 15, g = lane >> 4;
  const float scale = 0.125f;

  bf16x8 qh[2], ql[2];
  {
    const float* qp = qkv + ((size_t)(b * NN) + bi * 64 + w * 16 + q15) * QKVS + h * DHH;
#pragma unroll
    for (int ks = 0; ks < 2; ks++) {
      float4 x0 = *(const float4*)(qp + ks * 32 + g * 8);
      float4 x1 = *(const float4*)(qp + ks * 32 + g * 8 + 4);
      float xs[8] = {x0.x, x0.y, x0.z, x0.w, x1.x, x1.y, x1.z, x1.w};
#pragma unroll
      for (int e = 0; e < 8; e++) {
        __bf16 hv = (__bf16)xs[e];
        qh[ks][e] = hv;
        ql[ks][e] = (__bf16)(xs[e] - (float)hv);
      }
    }
  }
  int tr = t >> 4, kc = (t & 15) * 4;      // K: rows tr, tr+16, tr+32, tr+48
  int td = t >> 3, tb = (t & 7) * 8;       // V: rows td, td+32
  float4 kp0, kp1, kp2, kp3;
  uint4 vhp0, vhp1, vlp0, vlp1;

#define LOAD_TILE(jt_) do {                                                        \
    const float* kb_ = qkv + ((size_t)(b * NN) + (jt_) * 64 + tr) * QKVS + 512 +   \
                       h * DHH + kc;                                               \
    kp0 = *(const float4*)kb_;                                                     \
    kp1 = *(const float4*)(kb_ + (size_t)16 * QKVS);                               \
    kp2 = *(const float4*)(kb_ + (size_t)32 * QKVS);                               \
    kp3 = *(const float4*)(kb_ + (size_t)48 * QKVS);                               \
    size_t vb_ = ((size_t)(b * HH + h) * 64 + td) * NN + (jt_) * 64 + tb;          \
    vhp0 = *(const uint4*)(vth + vb_);                                             \
    vhp1 = *(const uint4*)(vth + vb_ + (size_t)32 * NN);                           \
    vlp0 = *(const uint4*)(vtl + vb_);                                             \
    vlp1 = *(const uint4*)(vtl + vb_ + (size_t)32 * NN);                           \
  } while (0)

#define STORE_K(kp_, ro_) do {                                                     \
    bf16x4 hv_, lv_;                                                               \
    float e0_ = kp_.x, e1_ = kp_.y, e2_ = kp_.z, e3_ = kp_.w;                      \
    hv_[0] = (__bf16)e0_; lv_[0] = (__bf16)(e0_ - (float)hv_[0]);                  \
    hv_[1] = (__bf16)e1_; lv_[1] = (__bf16)(e1_ - (float)hv_[1]);                  \
    hv_[2] = (__bf16)e2_; lv_[2] = (__bf16)(e2_ - (float)hv_[2]);                  \
    hv_[3] = (__bf16)e3_; lv_[3] = (__bf16)(e3_ - (float)hv_[3]);                  \
    *(bf16x4*)&Kh[((ro_) + tr) * 72 + kc] = hv_;                                   \
    *(bf16x4*)&Kl[((ro_) + tr) * 72 + kc] = lv_;                                   \
  } while (0)

  float m_run = -INFINITY, l_run = 0.f;
  f32x4 opv[4] = {};
  int ntiles = bi + 1;
  LOAD_TILE(0);
  for (int jt = 0; jt < ntiles; jt++) {
    __syncthreads();
    STORE_K(kp0, 0); STORE_K(kp1, 16); STORE_K(kp2, 32); STORE_K(kp3, 48);
    *(uint4*)&Vh[td * 72 + tb] = vhp0;
    *(uint4*)&Vh[(32 + td) * 72 + tb] = vhp1;
    *(uint4*)&Vl[td * 72 + tb] = vlp0;
    *(uint4*)&Vl[(32 + td) * 72 + tb] = vlp1;
    if (jt + 1 < ntiles) LOAD_TILE(jt + 1);
    __syncthreads();
    int smax = (jt == bi) ? w : 3;
    float sc16[16];
    float tmax = -INFINITY;
#pragma unroll
    for (int s = 0; s < 4; s++) {
      if (s <= smax) {
        f32x4 accs = {};
#pragma unroll
        for (int ks = 0; ks < 2; ks++) {
          bf16x8 ah = *(const bf16x8*)&Kh[(s * 16 + q15) * 72 + ks * 32 + g * 8];
          bf16x8 al = *(const bf16x8*)&Kl[(s * 16 + q15) * 72 + ks * 32 + g * 8];
          accs = __builtin_amdgcn_mfma_f32_16x16x32_bf16(ah, qh[ks], accs, 0, 0, 0);
          accs = __builtin_amdgcn_mfma_f32_16x16x32_bf16(al, qh[ks], accs, 0, 0, 0);
          accs = __builtin_amdgcn_mfma_f32_16x16x32_bf16(ah, ql[ks], accs, 0, 0, 0);
        }
#pragma unroll
        for (int r = 0; r < 4; r++) {
          float sv = accs[r] * scale;
          if (jt == bi) {
            int kvg = jt * 64 + s * 16 + g * 4 + r;
            int qg = bi * 64 + w * 16 + q15;
            if (kvg > qg) sv = -INFINITY;
          }
          sc16[s * 4 + r] = sv;
          tmax = fmaxf(tmax, sv);
        }
      } else {
#pragma unroll
        for (int r = 0; r < 4; r++) sc16[s * 4 + r] = -INFINITY;
      }
    }
    tmax = fmaxf(tmax, __shfl_xor(tmax, 16, 64));
    tmax = fmaxf(tmax, __shfl_xor(tmax, 32, 64));
    float m_new = fmaxf(m_run, tmax);
    float psum = 0.f;
    __bf16 ph[16], pl[16];
#pragma unroll
    for (int i = 0; i < 16; i++) {
      float p = __expf(sc16[i] - m_new);
      psum += p;
      __bf16 hp = (__bf16)p;
      ph[i] = hp; pl[i] = (__bf16)(p - (float)hp);
    }
    psum += __shfl_xor(psum, 16, 64);
    psum += __shfl_xor(psum, 32, 64);
    float alpha = __expf(m_run - m_new);
    l_run = l_run * alpha + psum;
    m_run = m_new;
    __bf16* Ph = Pw + (w * 2 + 0) * 1152;
    __bf16* Pl = Pw + (w * 2 + 1) * 1152;
#pragma unroll
    for (int s = 0; s < 4; s++) {
      bf16x4 hv, lv;
#pragma unroll
      for (int r = 0; r < 4; r++) { hv[r] = ph[s * 4 + r]; lv[r] = pl[s * 4 + r]; }
      *(bf16x4*)&Ph[q15 * 72 + s * 16 + g * 4] = hv;
      *(bf16x4*)&Pl[q15 * 72 + s * 16 + g * 4] = lv;
    }
    __builtin_amdgcn_wave_barrier();
    float a0 = __shfl(alpha, g * 4 + 0, 64);
    float a1 = __shfl(alpha, g * 4 + 1, 64);
    float a2 = __shfl(alpha, g * 4 + 2, 64);
    float a3 = __shfl(alpha, g * 4 + 3, 64);
#pragma unroll
    for (int dsub = 0; dsub < 4; dsub++) {
      opv[dsub][0] *= a0; opv[dsub][1] *= a1;
      opv[dsub][2] *= a2; opv[dsub][3] *= a3;
    }
#pragma unroll
    for (int ks2 = 0; ks2 < 2; ks2++) {
      bf16x8 pah = *(const bf16x8*)&Ph[q15 * 72 + ks2 * 32 + g * 8];
      bf16x8 pal = *(const bf16x8*)&Pl[q15 * 72 + ks2 * 32 + g * 8];
#pragma unroll
      for (int dsub = 0; dsub < 4; dsub++) {
        bf16x8 vbh = *(const bf16x8*)&Vh[(dsub * 16 + q15) * 72 + ks2 * 32 + g * 8];
        bf16x8 vbl = *(const bf16x8*)&Vl[(dsub * 16 + q15) * 72 + ks2 * 32 + g * 8];
        opv[dsub] = __builtin_amdgcn_mfma_f32_16x16x32_bf16(pah, vbh, opv[dsub], 0, 0, 0);
        opv[dsub] = __builtin_amdgcn_mfma_f32_16x16x32_bf16(pal, vbh, opv[dsub], 0, 0, 0);
        opv[dsub] = __builtin_amdgcn_mfma_f32_16x16x32_bf16(pah, vbl, opv[dsub], 0, 0, 0);
      }
    }
  }
#undef LOAD_TILE
#undef STORE_K
  __syncthreads();
  float* scf  = (float*)smem;                 // [64][68] fp32
  float* marr = (float*)(smem + 8704);
  float* larr = marr + 64;
  float* aarr = marr + 128;
  float* sc2  = (float*)(smem + 9216);        // [64][33] fp32
  int*   pidx = (int*)(smem + 13824);         // [64][32] int
#pragma unroll
  for (int dsub = 0; dsub < 4; dsub++)
#pragma unroll
    for (int r = 0; r < 4; r++)
      scf[(w * 16 + g * 4 + r) * 68 + dsub * 16 + q15] = opv[dsub][r];
  if (g == 0) { marr[w * 16 + q15] = m_run; larr[w * 16 + q15] = l_run; }
  __syncthreads();
  int r_ = t & 63, w4 = t >> 6;
  float acc16[16];
  if (knn) {
    size_t rowbase = ((size_t)b * HH + h) * NN + bi * 64;
    for (int rr = w * 16; rr < w * 16 + 16; rr++) {
      float s = (lane < TOPKK) ? topv[(rowbase + rr) * TOPKK + lane] : -INFINITY;
      float m_old = marr[rr];
      float tm = s;
#pragma unroll
      for (int m = 32; m; m >>= 1) tm = fmaxf(tm, __shfl_xor(tm, m, 64));
      float m_new = fmaxf(m_old, tm);
      float p = __expf(s - m_new);
      float ts = p;
#pragma unroll
      for (int m = 32; m; m >>= 1) ts += __shfl_xor(ts, m, 64);
      float alpha = __expf(m_old - m_new);
      if (lane < TOPKK) {
        sc2[rr * 33 + lane] = p;
        pidx[rr * 32 + lane] = topi[(rowbase + rr) * TOPKK + lane];
      }
      if (lane == 0) {
        marr[rr] = m_new; larr[rr] = larr[rr] * alpha + ts; aarr[rr] = alpha;
      }
    }
    __syncthreads();
    float al = aarr[r_];
#pragma unroll
    for (int dd = 0; dd < 16; dd++) acc16[dd] = scf[r_ * 68 + w4 * 16 + dd] * al;
    const float* mvb = mem_v + (size_t)b * MEMM * DHH;
#pragma unroll 1
    for (int kk = 0; kk < TOPKK; kk++) {
      float p = sc2[r_ * 33 + kk];
      const float* mrow = mvb + (size_t)pidx[r_ * 32 + kk] * DHH + w4 * 16;
#pragma unroll
      for (int dd = 0; dd < 16; dd += 4) {
        float4 m4 = *(const float4*)(mrow + dd);
        acc16[dd] += p * m4.x; acc16[dd + 1] += p * m4.y;
        acc16[dd + 2] += p * m4.z; acc16[dd + 3] += p * m4.w;
      }
    }
  } else {
#pragma unroll
    for (int dd = 0; dd < 16; dd++) acc16[dd] = scf[r_ * 68 + w4 * 16 + dd];
  }
  float linv = 1.f / larr[r_];
  bf16x8 o0, o1;
#pragma unroll
  for (int j = 0; j < 8; j++) {
    o0[j] = (__bf16)(acc16[j] * linv);
    o1[j] = (__bf16)(acc16[8 + j] * linv);
  }
  __bf16* aop = ao + ((size_t)(b * NN) + bi * 64 + r_) * DD + h * DHH + w4 * 16;
  *(bf16x8*)aop = o0;
  *(bf16x8*)(aop + 8) = o1;
}

// ---------------- host ----------------
extern "C" void kernel_launch(void* const* d_in, const int* in_sizes, int n_in,
                              void* d_out, int out_size, void* d_ws, size_t ws_size,
                              hipStream_t stream) {
  const float* x_in  = (const float*)d_in[0];
  const float* Wq    = (const float*)d_in[1];
  const float* Wk    = (const float*)d_in[2];
  const float* Wv    = (const float*)d_in[3];
  const float* Wo    = (const float*)d_in[4];
  const float* ln1_s = (const float*)d_in[5];
  const float* ln1_b = (const float*)d_in[6];
  const float* ln2_s = (const float*)d_in[7];
  const float* ln2_b = (const float*)d_in[8];
  const float* W1    = (const float*)d_in[9];
  const float* W2    = (const float*)d_in[10];
  const float* lnf_s = (const float*)d_in[11];
  const float* lnf_b = (const float*)d_in[12];
  const float* mem_k = (const float*)d_in[13];
  const float* mem_v = (const float*)d_in[14];

  float* ws  = (float*)d_ws;
  float*  xb    = ws;
  float*  qkvb  = ws + 2097152;           // [4096][1536] fp32
  __bf16* hb16  = (__bf16*)(ws + 8388608);
  __bf16* ao16  = (__bf16*)(ws + 9437184);
  __bf16* wqT   = (__bf16*)(ws + 10485760);   // wq/wk/wv contiguous [1536][512]
  __bf16* woT   = (__bf16*)(ws + 10878976);
  __bf16* w1T   = (__bf16*)(ws + 11010048);
  __bf16* w2T   = (__bf16*)(ws + 11534336);
  float*  tvb   = ws + 12058624;
  int*    tib   = (int*)(ws + 13107200);
  __bf16* ffb16 = (__bf16*)(ws + 2097152);    // aliases qkvb (dead post-attn)
  __bf16* wkT   = wqT + 262144;
  __bf16* wvT   = wqT + 524288;
  __bf16* khi16 = (__bf16*)(ws + 8388608);
  __bf16* klo16 = (__bf16*)(ws + 9437184);

  // S chunk region after base layout; S is now bf16 (half the round-trip,
  // 64 MB chunk at nbh=16 -> mostly L3-resident). vth/vtl overlap its start
  // (lifetime-disjoint as before). nbh sizing kept at fp32 slice size
  // (conservative; chunking behavior unchanged).
  const size_t base_floats = 14155776;
  const size_t slice_floats = (size_t)NN * MEMM;
  const size_t ws_floats = ws_size / sizeof(float);
  int nbh = 0;
  for (int c = 64; c >= 1; c >>= 1) {
    if (base_floats + (size_t)c * slice_floats <= ws_floats) { nbh = c; break; }
  }
  __bf16* Sb16 = (__bf16*)(ws + base_floats);
  __bf16* vth = (__bf16*)(ws + base_floats);
  __bf16* vtl = (__bf16*)(ws + base_floats + 1048576);

  dim3 blk(256);
  const size_t DD2 = (size_t)DD * DD;
  for (int l = 0; l < DEPTHH; l++) {
    const float* xcur = (l == 0) ? x_in : xb;
    transpose_all_kernel<<<dim3(3072), blk, 0, stream>>>(
        Wq + l * DD2, Wk + l * DD2, Wv + l * DD2, Wo + l * DD2,
        W1 + (size_t)l * DD * FFF, W2 + (size_t)l * FFF * DD,
        wqT, wkT, wvT, woT, w1T, w2T);

    ln_kernel<1><<<NT, blk, 0, stream>>>(xcur, ln1_s + l * DD, ln1_b + l * DD, hb16);
    gemm_mfma64<0, 0><<<dim3(24, 32), blk, 0, stream>>>(hb16, wqT, nullptr, qkvb, NT, QKVS, DD);
    int mi = (l == 3) ? 0 : ((l == 4) ? 1 : -1);
    if (mi >= 0) {
      const float* mk = mem_k + (size_t)mi * BB * MEMM * DHH;
      split_bf16_kernel<<<dim3(BB * MEMM * DHH / 1024), blk, 0, stream>>>(mk, khi16, klo16);
      if (nbh > 0) {
        for (int bh0 = 0; bh0 < BB * HH; bh0 += nbh) {
          knn_score_mfma<<<dim3(16, nbh, MSPLIT), blk, 0, stream>>>(qkvb, khi16, klo16, Sb16, bh0);
          knn_select_kernel<<<dim3(nbh * NN / 4), blk, 0, stream>>>(Sb16, tvb, tib, bh0 * NN);
        }
      } else {
        knn_mfma_topk<<<dim3(16, 8, 8), blk, 0, stream>>>(qkvb, khi16, klo16, tvb, tib);
      }
    }
    vtrans_split_kernel<<<dim3(8, 8, 8), blk, 0, stream>>>(qkvb, vth, vtl);
    attn_mfma_kernel<<<dim3(512), blk, 0, stream>>>(
        qkvb, vth, vtl, ao16, tvb, tib,
        mem_v + (size_t)(mi < 0 ? 0 : mi) * BB * MEMM * DHH, mi >= 0 ? 1 : 0);
    gemm_mfma64<2, 0><<<dim3(8, 32), blk, 0, stream>>>(ao16, woT, xcur, xb, NT, DD, DD);
    ln_kernel<1><<<NT, blk, 0, stream>>>(xb, ln2_s + l * DD, ln2_b + l * DD, hb16);
    gemm_mfma128<1, 1><<<dim3(16, 32), blk, 0, stream>>>(hb16, w1T, nullptr, ffb16, NT, FFF, DD);
    gemm_mfma64<2, 0><<<dim3(8, 32), blk, 0, stream>>>(ffb16, w2T, xb, xb, NT, DD, FFF);
  }
  ln_kernel<0><<<NT, blk, 0, stream>>>(xb, lnf_s, lnf_b, (float*)d_out);
}